// Round 3
// baseline (2854.303 us; speedup 1.0000x reference)
//
#include <hip/hip_runtime.h>
#include <hip/hip_bf16.h>

// CodeformerLM — round 3: f32 inputs, f32 OUTPUT (reference returns float32).
// All intermediates f32 (correctness baseline); MFMA conversion next round.

typedef __hip_bfloat16 bf16;

__device__ inline float gelu_f(float x) {
    // jax.nn.gelu approximate=True (tanh form)
    return 0.5f * x * (1.f + tanhf(0.7978845608028654f * (x + 0.044715f * x * x * x)));
}

// ---------------- LayerNorm (H=512, block=256, one row per block) ----------------
__device__ inline void ln_finish(float v0, float v1, const float* __restrict__ lnw,
                                 float* __restrict__ outrow) {
    float s = v0 + v1, q = v0 * v0 + v1 * v1;
#pragma unroll
    for (int o = 32; o > 0; o >>= 1) { s += __shfl_xor(s, o); q += __shfl_xor(q, o); }
    __shared__ float rs[4], rq[4];
    int w = threadIdx.x >> 6;
    if ((threadIdx.x & 63) == 0) { rs[w] = s; rq[w] = q; }
    __syncthreads();
    s = rs[0] + rs[1] + rs[2] + rs[3];
    q = rq[0] + rq[1] + rq[2] + rq[3];
    float m = s * (1.f / 512.f);
    float var = q * (1.f / 512.f) - m * m;
    float inv = rsqrtf(var + 1e-7f);
    int h = threadIdx.x;
    outrow[h]       = (v0 - m) * inv * lnw[h]       + lnw[512 + h];
    outrow[h + 256] = (v1 - m) * inv * lnw[h + 256] + lnw[768 + h];
}

// out[row] = LN(emb[ids[row]])
__global__ __launch_bounds__(256) void k_embed_ln(const int* __restrict__ ids,
        const float* __restrict__ emb, const float* __restrict__ lnw, float* __restrict__ out) {
    int row = blockIdx.x;
    const float* e = emb + (long)ids[row] * 512;
    float v0 = e[threadIdx.x];
    float v1 = e[threadIdx.x + 256];
    ln_finish(v0, v1, lnw, out + (long)row * 512);
}

// out[row] = LN(a[row] + (b ? b[row] : 0))
__global__ __launch_bounds__(256) void k_add_ln(const float* __restrict__ a, const float* __restrict__ b,
        const float* __restrict__ lnw, float* __restrict__ out) {
    int row = blockIdx.x;
    long off = (long)row * 512;
    float v0 = a[off + threadIdx.x];
    float v1 = a[off + threadIdx.x + 256];
    if (b) { v0 += b[off + threadIdx.x]; v1 += b[off + threadIdx.x + 256]; }
    ln_finish(v0, v1, lnw, out + off);
}

// chunk_embs[bc] = LN(token_units[bc, pos0] + chunk_pos[bc%16])
__global__ __launch_bounds__(256) void k_chunk_ln(const float* __restrict__ tu, const float* __restrict__ cpos,
        const float* __restrict__ lnw, float* __restrict__ out) {
    int bc = blockIdx.x;
    int c = bc & 15;
    long toff = (long)bc * 64 * 512;
    float v0 = tu[toff + threadIdx.x]       + cpos[c * 512 + threadIdx.x];
    float v1 = tu[toff + threadIdx.x + 256] + cpos[c * 512 + threadIdx.x + 256];
    ln_finish(v0, v1, lnw, out + (long)bc * 512);
}

// ---------------- Decoder-input build: (B*C, 80, 512) ----------------
__global__ __launch_bounds__(256) void k_dec_in(const float* __restrict__ chunk_units,
        const float* __restrict__ sos, const float* __restrict__ dec_tok,
        const int* __restrict__ num_chunks, const int* __restrict__ num_tokens,
        float* __restrict__ out) {
    int row = blockIdx.x;          // bc*80 + p
    int p = row % 80;
    int bc = row / 80;
    int c = bc & 15, b = bc >> 4;
    const float* src = nullptr;
    if (c < num_chunks[b]) {
        if (p <= c) {
            src = (p == 0) ? sos : chunk_units + ((long)(b * 16 + p - 1)) * 512;
        } else {
            int n = num_tokens[bc];
            if (p <= c + n) src = dec_tok + ((long)bc * 64 + (p - c - 1)) * 512;
        }
    }
    long off = (long)row * 512;
    out[off + threadIdx.x]       = src ? src[threadIdx.x] : 0.f;
    out[off + threadIdx.x + 256] = src ? src[threadIdx.x + 256] : 0.f;
}

// ---------------- Head gather ----------------
__global__ __launch_bounds__(256) void k_head_gather(const float* __restrict__ units,
        const int* __restrict__ num_chunks, const int* __restrict__ num_tokens,
        float* __restrict__ out) {
    int row = blockIdx.x;          // bc*63 + t
    int t = row % 63;
    int bc = row / 63;
    int c = bc & 15, b = bc >> 4;
    bool valid = (c < num_chunks[b]) && (t < num_tokens[bc] - 1);
    const float* src = valid ? units + ((long)bc * 80 + (c + 1 + t)) * 512 : nullptr;
    long off = (long)row * 512;
    out[off + threadIdx.x]       = src ? src[threadIdx.x] : 0.f;
    out[off + threadIdx.x + 256] = src ? src[threadIdx.x + 256] : 0.f;
}

// ---------------- Fused attention: one block per (seq, head). dh=64, NH=8, S<=80 ----------------
__global__ __launch_bounds__(256) void k_attn(const float* __restrict__ qkv, float* __restrict__ att,
        const int* __restrict__ limits, int causal, int S) {
    __shared__ float Qs[80][65], Ks[80][65], Vs[80][65];   // +1 pad
    __shared__ float ps[4][80];
    int seq = blockIdx.x >> 3, h = blockIdx.x & 7;
    const float* base = qkv + (long)seq * S * 1536 + h * 64;
    for (int idx = threadIdx.x; idx < S * 64; idx += 256) {
        int i = idx >> 6, d = idx & 63;
        const float* r = base + (long)i * 1536 + d;
        Qs[i][d] = r[0];
        Ks[i][d] = r[512];
        Vs[i][d] = r[1024];
    }
    __syncthreads();
    int w = threadIdx.x >> 6, lane = threadIdx.x & 63;
    int lim = limits ? limits[seq] : S;
    for (int i = w; i < S; i += 4) {
        int kmax = causal ? (i + 1) : S;
        if (lim < kmax) kmax = lim;      // kmax >= 1 always
        float s0 = -1e30f, s1 = -1e30f;
        if (lane < kmax) {
            float a = 0.f;
#pragma unroll
            for (int d = 0; d < 64; ++d) a += Qs[i][d] * Ks[lane][d];
            s0 = a * 0.125f;
        }
        if (lane + 64 < kmax) {
            float a = 0.f;
#pragma unroll
            for (int d = 0; d < 64; ++d) a += Qs[i][d] * Ks[lane + 64][d];
            s1 = a * 0.125f;
        }
        float mx = fmaxf(s0, s1);
#pragma unroll
        for (int o = 32; o > 0; o >>= 1) mx = fmaxf(mx, __shfl_xor(mx, o));
        float e0 = (lane < kmax) ? expf(s0 - mx) : 0.f;
        float e1 = (lane + 64 < kmax) ? expf(s1 - mx) : 0.f;
        float sm = e0 + e1;
#pragma unroll
        for (int o = 32; o > 0; o >>= 1) sm += __shfl_xor(sm, o);
        float rinv = 1.f / sm;
        ps[w][lane] = e0 * rinv;
        if (lane + 64 < S) ps[w][lane + 64] = e1 * rinv;
        __syncthreads();
        float acc = 0.f;
        for (int j = 0; j < kmax; ++j) acc += ps[w][j] * Vs[j][lane];
        att[((long)seq * S + i) * 512 + h * 64 + lane] = acc;
        __syncthreads();
    }
}

// ---------------- GEMM: C[M][N] = act(A[M][K] @ B[K][N] (+bias)) ----------------
// 64x64 tile, 256 threads, 4x4 accum/thread, K-tile 16. OUTBF: store bf16 else f32.
template<int ACT, int BIAS, int OUTBF>
__global__ __launch_bounds__(256) void k_gemm(const float* __restrict__ A, const float* __restrict__ Bm,
        const float* __restrict__ bias, void* __restrict__ Cc, int M, int N, int K) {
    __shared__ float As[16][64];   // As[k][m]
    __shared__ float Bs[16][64];   // Bs[k][n]
    int m0 = blockIdx.y * 64, n0 = blockIdx.x * 64;
    int tid = threadIdx.x;
    int tx = tid & 15, ty = tid >> 4;
    int am = tid >> 2, ak = (tid & 3) * 4;     // A loader: row am, k-chunk ak (float4)
    int bk = tid >> 4, bn = (tid & 15) * 4;    // B loader: k-row bk, n-chunk bn (float4)
    float acc[4][4] = {};
    for (int k0 = 0; k0 < K; k0 += 16) {
        int gm = m0 + am;
        if (gm < M) {
            float4 t4 = *reinterpret_cast<const float4*>(A + (long)gm * K + k0 + ak);
            As[ak + 0][am] = t4.x;
            As[ak + 1][am] = t4.y;
            As[ak + 2][am] = t4.z;
            As[ak + 3][am] = t4.w;
        } else {
            As[ak + 0][am] = 0.f; As[ak + 1][am] = 0.f;
            As[ak + 2][am] = 0.f; As[ak + 3][am] = 0.f;
        }
        *reinterpret_cast<float4*>(&Bs[bk][bn]) =
            *reinterpret_cast<const float4*>(Bm + (long)(k0 + bk) * N + n0 + bn);
        __syncthreads();
#pragma unroll
        for (int kk = 0; kk < 16; ++kk) {
            float4 a4 = *reinterpret_cast<const float4*>(&As[kk][ty * 4]);
            float4 b4 = *reinterpret_cast<const float4*>(&Bs[kk][tx * 4]);
            float av[4] = {a4.x, a4.y, a4.z, a4.w};
            float bv[4] = {b4.x, b4.y, b4.z, b4.w};
#pragma unroll
            for (int i = 0; i < 4; ++i)
#pragma unroll
                for (int j = 0; j < 4; ++j) acc[i][j] += av[i] * bv[j];
        }
        __syncthreads();
    }
#pragma unroll
    for (int i = 0; i < 4; ++i) {
        int gm = m0 + ty * 4 + i;
        if (gm < M) {
#pragma unroll
            for (int j = 0; j < 4; ++j) {
                int gn = n0 + tx * 4 + j;
                float v = acc[i][j];
                if (BIAS) v += bias[gn];
                if (ACT == 1) v = gelu_f(v);
                if (OUTBF) ((bf16*)Cc)[(long)gm * N + gn] = __float2bfloat16(v);
                else       ((float*)Cc)[(long)gm * N + gn] = v;
            }
        }
    }
}

// ---------------- Encoder driver (L=2 layers) ----------------
static void run_encoder(hipStream_t st, float* x, int nseq, int S, const int* limits, int causal,
                        const float* wqkv, const float* wo, const float* ln1,
                        const float* w1, const float* w2, const float* ln2,
                        float* qkv, float* att, float* proj, float* x2, float* h1) {
    int R = nseq * S;
    int gy = (R + 63) / 64;
    for (int l = 0; l < 2; ++l) {
        k_gemm<0, 0, 0><<<dim3(1536 / 64, gy), 256, 0, st>>>(x, wqkv + (long)l * 512 * 1536, nullptr, qkv, R, 1536, 512);
        k_attn<<<dim3(nseq * 8), 256, 0, st>>>(qkv, att, limits, causal, S);
        k_gemm<0, 0, 0><<<dim3(512 / 64, gy), 256, 0, st>>>(att, wo + (long)l * 512 * 512, nullptr, proj, R, 512, 512);
        k_add_ln<<<dim3(R), 256, 0, st>>>(x, proj, ln1 + (long)l * 1024, x2);
        k_gemm<1, 0, 0><<<dim3(2048 / 64, gy), 256, 0, st>>>(x2, w1 + (long)l * 512 * 2048, nullptr, h1, R, 2048, 512);
        k_gemm<0, 0, 0><<<dim3(512 / 64, gy), 256, 0, st>>>(h1, w2 + (long)l * 2048 * 512, nullptr, proj, R, 512, 2048);
        k_add_ln<<<dim3(R), 256, 0, st>>>(x2, proj, ln2 + (long)l * 1024, x);
    }
}

extern "C" void kernel_launch(void* const* d_in, const int* in_sizes, int n_in,
                              void* d_out, int out_size, void* d_ws, size_t ws_size,
                              hipStream_t stream) {
    (void)in_sizes; (void)n_in; (void)out_size; (void)ws_size;
    const int*   token_ids    = (const int*)d_in[0];
    const int*   num_chunks   = (const int*)d_in[1];
    const int*   num_tokens   = (const int*)d_in[2];
    const float* tok_emb      = (const float*)d_in[3];
    const float* tok_emb_ln   = (const float*)d_in[4];
    const float* chunk_pos    = (const float*)d_in[5];
    const float* chunk_emb_ln = (const float*)d_in[6];
    const float* sos          = (const float*)d_in[7];
    const float* dec_emb      = (const float*)d_in[8];
    const float* dec_emb_ln   = (const float*)d_in[9];
    const float* cls_dense    = (const float*)d_in[10];
    const float* cls_ln       = (const float*)d_in[11];
    const float* cls_proj     = (const float*)d_in[12];
    const float* cls_b        = (const float*)d_in[13];
    const float* tok_wqkv = (const float*)d_in[14];
    const float* tok_wo   = (const float*)d_in[15];
    const float* tok_ln1  = (const float*)d_in[16];
    const float* tok_w1   = (const float*)d_in[17];
    const float* tok_w2   = (const float*)d_in[18];
    const float* tok_ln2  = (const float*)d_in[19];
    const float* chk_wqkv = (const float*)d_in[20];
    const float* chk_wo   = (const float*)d_in[21];
    const float* chk_ln1  = (const float*)d_in[22];
    const float* chk_w1   = (const float*)d_in[23];
    const float* chk_w2   = (const float*)d_in[24];
    const float* chk_ln2  = (const float*)d_in[25];
    const float* dec_wqkv = (const float*)d_in[26];
    const float* dec_wo   = (const float*)d_in[27];
    const float* dec_ln1  = (const float*)d_in[28];
    const float* dec_w1   = (const float*)d_in[29];
    const float* dec_w2   = (const float*)d_in[30];
    const float* dec_ln2  = (const float*)d_in[31];

    // workspace carve (~75 MB, f32)
    char* p = (char*)d_ws;
    auto carve = [&](size_t elems) {
        float* r = (float*)p;
        p += ((elems * 4 + 255) / 256) * 256;
        return r;
    };
    float* x       = carve(2560 * 512);
    float* qkv     = carve(2560 * 1536);
    float* att     = carve(2560 * 512);
    float* proj    = carve(2560 * 512);
    float* x2      = carve(2560 * 512);
    float* h1      = carve(2560 * 2048);
    float* chunk_x = carve(32 * 512);
    float* dec_tok = carve(2048 * 512);
    float* unitsre = carve(2016 * 512);
    float* hbuf    = carve(2016 * 512);
    float* ybuf    = carve(2016 * 512);

    // 1) token encoder
    k_embed_ln<<<2048, 256, 0, stream>>>(token_ids, tok_emb, tok_emb_ln, x);
    run_encoder(stream, x, 32, 64, num_tokens, 0,
                tok_wqkv, tok_wo, tok_ln1, tok_w1, tok_w2, tok_ln2,
                qkv, att, proj, x2, h1);
    // 2) chunk encoder
    k_chunk_ln<<<32, 256, 0, stream>>>(x, chunk_pos, chunk_emb_ln, chunk_x);
    run_encoder(stream, chunk_x, 2, 16, num_chunks, 1,
                chk_wqkv, chk_wo, chk_ln1, chk_w1, chk_w2, chk_ln2,
                qkv, att, proj, x2, h1);
    // 3) decoder
    k_embed_ln<<<2048, 256, 0, stream>>>(token_ids, dec_emb, dec_emb_ln, dec_tok);
    k_dec_in<<<2560, 256, 0, stream>>>(chunk_x, sos, dec_tok, num_chunks, num_tokens, x);
    run_encoder(stream, x, 32, 80, nullptr, 1,
                dec_wqkv, dec_wo, dec_ln1, dec_w1, dec_w2, dec_ln2,
                qkv, att, proj, x2, h1);
    // 4) head
    k_head_gather<<<2016, 256, 0, stream>>>(x, num_chunks, num_tokens, unitsre);
    k_gemm<1, 0, 0><<<dim3(512 / 64, 32), 256, 0, stream>>>(unitsre, cls_dense, nullptr, hbuf, 2016, 512, 512);
    k_add_ln<<<2016, 256, 0, stream>>>(hbuf, nullptr, cls_ln, ybuf);
    // FINAL: f32 output (reference returns float32)
    k_gemm<0, 1, 0><<<dim3(32000 / 64, 32), 256, 0, stream>>>(ybuf, cls_proj, cls_b, d_out, 2016, 32000, 512);
}

// Round 4
// 1312.796 us; speedup vs baseline: 2.1742x; 2.1742x over previous
//
#include <hip/hip_runtime.h>
#include <hip/hip_bf16.h>

// CodeformerLM — round 4: bf16 MFMA GEMMs (f32 accum), f32 everything else.
// Weights pre-transposed+converted to bf16 [N][K] once per launch.

typedef __hip_bfloat16 bf16;
typedef __attribute__((ext_vector_type(8))) short short8;
typedef __attribute__((ext_vector_type(4))) float f32x4;

__device__ inline short f2bs(float x) {
    bf16 h = __float2bfloat16(x);
    return *reinterpret_cast<short*>(&h);
}
__device__ inline float gelu_f(float x) {
    return 0.5f * x * (1.f + tanhf(0.7978845608028654f * (x + 0.044715f * x * x * x)));
}

// ---------------- batched weight transpose+convert: W[K][N] f32 -> Wt[N][K] bf16 ----------------
#define NMAT 26
struct TAll {
    const float* src[NMAT];
    bf16* dst[NMAT];
    int K[NMAT], N[NMAT];
    int ofs[NMAT + 1];
};

__global__ __launch_bounds__(256) void k_transpose(TAll ta) {
    __shared__ float tile[32][33];
    int bid = blockIdx.x;
    int m = 0;
    while (m + 1 < NMAT && bid >= ta.ofs[m + 1]) ++m;
    int local = bid - ta.ofs[m];
    int K = ta.K[m], N = ta.N[m];
    int tilesX = N >> 5;
    int tx = local % tilesX, ty = local / tilesX;
    int k0 = ty << 5, n0 = tx << 5;
    const float* src = ta.src[m];
    bf16* dst = ta.dst[m];
    int t = threadIdx.x;
    int c = t & 31, r = t >> 5;   // 8 rows per pass
#pragma unroll
    for (int p = 0; p < 4; ++p)
        tile[r + p * 8][c] = src[(long)(k0 + r + p * 8) * N + n0 + c];
    __syncthreads();
#pragma unroll
    for (int p = 0; p < 4; ++p)
        dst[(long)(n0 + r + p * 8) * K + k0 + c] = __float2bfloat16(tile[c][r + p * 8]);
}

// ---------------- MFMA GEMM: C[M][N] = act(A[M][K] @ B[K][N] (+bias)) ----------------
// A: f32 row-major (converted to bf16 at staging). Bt: bf16 [N][K] (pre-transposed).
// BN=128 fixed, BM in {64,128}. 4 waves (2x2), 16x16x32 bf16 MFMA, BK=64, f32 accum.
// LDS rows padded to 72 shorts (144B): fragment reads are 2-way bank aliased (free).
template<int BM, int ACT, int BIAS>
__global__ __launch_bounds__(256) void k_gemm_mfma(const float* __restrict__ A,
        const bf16* __restrict__ Bt, const float* __restrict__ bias,
        float* __restrict__ Cc, int M, int N, int K) {
    constexpr int WM = BM / 2;         // wave tile rows
    constexpr int FM = WM / 16;        // A fragments per wave
    constexpr int FN = 4;              // B fragments per wave (WN=64)
    __shared__ __align__(16) short As[BM][72];
    __shared__ __align__(16) short Bs[128][72];
    int tid = threadIdx.x;
    int w = tid >> 6, l = tid & 63;
    int wm = w >> 1, wn = w & 1;
    int l16 = l & 15, kg = l >> 4;
    int m0 = blockIdx.y * BM, n0 = blockIdx.x * 128;
    f32x4 acc[FM][FN];
#pragma unroll
    for (int i = 0; i < FM; ++i)
#pragma unroll
        for (int j = 0; j < FN; ++j) acc[i][j] = 0.f;

    int sr = tid >> 3;                 // staging row (32 rows/pass)
    int sk = (tid & 7) * 8;            // staging k-chunk (8 elems)
    for (int k0 = 0; k0 < K; k0 += 64) {
        // stage A (f32 -> bf16)
#pragma unroll
        for (int p = 0; p < BM / 32; ++p) {
            int r = sr + p * 32;
            int gm = m0 + r;
            short8 s;
            if (gm < M) {
                const float* srcp = A + (long)gm * K + k0 + sk;
                float4 u = *reinterpret_cast<const float4*>(srcp);
                float4 v = *reinterpret_cast<const float4*>(srcp + 4);
                s[0] = f2bs(u.x); s[1] = f2bs(u.y); s[2] = f2bs(u.z); s[3] = f2bs(u.w);
                s[4] = f2bs(v.x); s[5] = f2bs(v.y); s[6] = f2bs(v.z); s[7] = f2bs(v.w);
            } else {
#pragma unroll
                for (int q = 0; q < 8; ++q) s[q] = 0;
            }
            *reinterpret_cast<short8*>(&As[r][sk]) = s;
        }
        // stage B (already bf16, [N][K] row-major)
#pragma unroll
        for (int p = 0; p < 4; ++p) {
            int n = sr + p * 32;
            *reinterpret_cast<short8*>(&Bs[n][sk]) =
                *reinterpret_cast<const short8*>(Bt + (long)(n0 + n) * K + k0 + sk);
        }
        __syncthreads();
#pragma unroll
        for (int ks = 0; ks < 2; ++ks) {
            short8 a[FM], b[FN];
#pragma unroll
            for (int i = 0; i < FM; ++i)
                a[i] = *reinterpret_cast<const short8*>(&As[wm * WM + i * 16 + l16][ks * 32 + kg * 8]);
#pragma unroll
            for (int j = 0; j < FN; ++j)
                b[j] = *reinterpret_cast<const short8*>(&Bs[wn * 64 + j * 16 + l16][ks * 32 + kg * 8]);
#pragma unroll
            for (int i = 0; i < FM; ++i)
#pragma unroll
                for (int j = 0; j < FN; ++j)
                    acc[i][j] = __builtin_amdgcn_mfma_f32_16x16x32_bf16(a[i], b[j], acc[i][j], 0, 0, 0);
        }
        __syncthreads();
    }
    // epilogue: D col = lane&15, row = (lane>>4)*4 + reg  (m89-verified)
#pragma unroll
    for (int i = 0; i < FM; ++i) {
#pragma unroll
        for (int jj = 0; jj < 4; ++jj) {
            int row = m0 + wm * WM + i * 16 + kg * 4 + jj;
            if (row < M) {
#pragma unroll
                for (int j = 0; j < FN; ++j) {
                    int col = n0 + wn * 64 + j * 16 + l16;
                    float v = acc[i][j][jj];
                    if (BIAS) v += bias[col];
                    if (ACT) v = gelu_f(v);
                    Cc[(long)row * N + col] = v;
                }
            }
        }
    }
}

// ---------------- LayerNorm (H=512, block=256, one row per block) ----------------
__device__ inline void ln_finish(float v0, float v1, const float* __restrict__ lnw,
                                 float* __restrict__ outrow) {
    float s = v0 + v1, q = v0 * v0 + v1 * v1;
#pragma unroll
    for (int o = 32; o > 0; o >>= 1) { s += __shfl_xor(s, o); q += __shfl_xor(q, o); }
    __shared__ float rs[4], rq[4];
    int w = threadIdx.x >> 6;
    if ((threadIdx.x & 63) == 0) { rs[w] = s; rq[w] = q; }
    __syncthreads();
    s = rs[0] + rs[1] + rs[2] + rs[3];
    q = rq[0] + rq[1] + rq[2] + rq[3];
    float m = s * (1.f / 512.f);
    float var = q * (1.f / 512.f) - m * m;
    float inv = rsqrtf(var + 1e-7f);
    int h = threadIdx.x;
    outrow[h]       = (v0 - m) * inv * lnw[h]       + lnw[512 + h];
    outrow[h + 256] = (v1 - m) * inv * lnw[h + 256] + lnw[768 + h];
}

__global__ __launch_bounds__(256) void k_embed_ln(const int* __restrict__ ids,
        const float* __restrict__ emb, const float* __restrict__ lnw, float* __restrict__ out) {
    int row = blockIdx.x;
    const float* e = emb + (long)ids[row] * 512;
    ln_finish(e[threadIdx.x], e[threadIdx.x + 256], lnw, out + (long)row * 512);
}

__global__ __launch_bounds__(256) void k_add_ln(const float* __restrict__ a, const float* __restrict__ b,
        const float* __restrict__ lnw, float* __restrict__ out) {
    int row = blockIdx.x;
    long off = (long)row * 512;
    float v0 = a[off + threadIdx.x];
    float v1 = a[off + threadIdx.x + 256];
    if (b) { v0 += b[off + threadIdx.x]; v1 += b[off + threadIdx.x + 256]; }
    ln_finish(v0, v1, lnw, out + off);
}

__global__ __launch_bounds__(256) void k_chunk_ln(const float* __restrict__ tu, const float* __restrict__ cpos,
        const float* __restrict__ lnw, float* __restrict__ out) {
    int bc = blockIdx.x;
    int c = bc & 15;
    long toff = (long)bc * 64 * 512;
    float v0 = tu[toff + threadIdx.x]       + cpos[c * 512 + threadIdx.x];
    float v1 = tu[toff + threadIdx.x + 256] + cpos[c * 512 + threadIdx.x + 256];
    ln_finish(v0, v1, lnw, out + (long)bc * 512);
}

// ---------------- Decoder-input build ----------------
__global__ __launch_bounds__(256) void k_dec_in(const float* __restrict__ chunk_units,
        const float* __restrict__ sos, const float* __restrict__ dec_tok,
        const int* __restrict__ num_chunks, const int* __restrict__ num_tokens,
        float* __restrict__ out) {
    int row = blockIdx.x;
    int p = row % 80;
    int bc = row / 80;
    int c = bc & 15, b = bc >> 4;
    const float* src = nullptr;
    if (c < num_chunks[b]) {
        if (p <= c) {
            src = (p == 0) ? sos : chunk_units + ((long)(b * 16 + p - 1)) * 512;
        } else {
            int n = num_tokens[bc];
            if (p <= c + n) src = dec_tok + ((long)bc * 64 + (p - c - 1)) * 512;
        }
    }
    long off = (long)row * 512;
    out[off + threadIdx.x]       = src ? src[threadIdx.x] : 0.f;
    out[off + threadIdx.x + 256] = src ? src[threadIdx.x + 256] : 0.f;
}

// ---------------- Head gather ----------------
__global__ __launch_bounds__(256) void k_head_gather(const float* __restrict__ units,
        const int* __restrict__ num_chunks, const int* __restrict__ num_tokens,
        float* __restrict__ out) {
    int row = blockIdx.x;
    int t = row % 63;
    int bc = row / 63;
    int c = bc & 15, b = bc >> 4;
    bool valid = (c < num_chunks[b]) && (t < num_tokens[bc] - 1);
    const float* src = valid ? units + ((long)bc * 80 + (c + 1 + t)) * 512 : nullptr;
    long off = (long)row * 512;
    out[off + threadIdx.x]       = src ? src[threadIdx.x] : 0.f;
    out[off + threadIdx.x + 256] = src ? src[threadIdx.x + 256] : 0.f;
}

// ---------------- Fused attention (f32): one block per (seq, head) ----------------
__global__ __launch_bounds__(256) void k_attn(const float* __restrict__ qkv, float* __restrict__ att,
        const int* __restrict__ limits, int causal, int S) {
    __shared__ float Qs[80][65], Ks[80][65], Vs[80][65];
    __shared__ float ps[4][80];
    int seq = blockIdx.x >> 3, h = blockIdx.x & 7;
    const float* base = qkv + (long)seq * S * 1536 + h * 64;
    for (int idx = threadIdx.x; idx < S * 64; idx += 256) {
        int i = idx >> 6, d = idx & 63;
        const float* r = base + (long)i * 1536 + d;
        Qs[i][d] = r[0];
        Ks[i][d] = r[512];
        Vs[i][d] = r[1024];
    }
    __syncthreads();
    int w = threadIdx.x >> 6, lane = threadIdx.x & 63;
    int lim = limits ? limits[seq] : S;
    for (int i = w; i < S; i += 4) {
        int kmax = causal ? (i + 1) : S;
        if (lim < kmax) kmax = lim;
        float s0 = -1e30f, s1 = -1e30f;
        if (lane < kmax) {
            float a = 0.f;
#pragma unroll
            for (int d = 0; d < 64; ++d) a += Qs[i][d] * Ks[lane][d];
            s0 = a * 0.125f;
        }
        if (lane + 64 < kmax) {
            float a = 0.f;
#pragma unroll
            for (int d = 0; d < 64; ++d) a += Qs[i][d] * Ks[lane + 64][d];
            s1 = a * 0.125f;
        }
        float mx = fmaxf(s0, s1);
#pragma unroll
        for (int o = 32; o > 0; o >>= 1) mx = fmaxf(mx, __shfl_xor(mx, o));
        float e0 = (lane < kmax) ? expf(s0 - mx) : 0.f;
        float e1 = (lane + 64 < kmax) ? expf(s1 - mx) : 0.f;
        float sm = e0 + e1;
#pragma unroll
        for (int o = 32; o > 0; o >>= 1) sm += __shfl_xor(sm, o);
        float rinv = 1.f / sm;
        ps[w][lane] = e0 * rinv;
        if (lane + 64 < S) ps[w][lane + 64] = e1 * rinv;
        __syncthreads();
        float acc = 0.f;
        for (int j = 0; j < kmax; ++j) acc += ps[w][j] * Vs[j][lane];
        att[((long)seq * S + i) * 512 + h * 64 + lane] = acc;
        __syncthreads();
    }
}

// ---------------- Encoder driver (L=2 layers) ----------------
// wts: per layer {Wt_qkv[1536][512], Wt_wo[512][512], Wt_w1[2048][512], Wt_w2[512][2048]}
static void run_encoder(hipStream_t st, float* x, int nseq, int S, const int* limits, int causal,
                        bf16* const* wts, const float* ln1, const float* ln2,
                        float* qkv, float* att, float* proj, float* x2, float* h1) {
    int R = nseq * S;
    int gy1 = (R + 127) / 128, gy0 = (R + 63) / 64;
    for (int l = 0; l < 2; ++l) {
        k_gemm_mfma<128, 0, 0><<<dim3(12, gy1), 256, 0, st>>>(x, wts[l * 4 + 0], nullptr, qkv, R, 1536, 512);
        k_attn<<<dim3(nseq * 8), 256, 0, st>>>(qkv, att, limits, causal, S);
        k_gemm_mfma<64, 0, 0><<<dim3(4, gy0), 256, 0, st>>>(att, wts[l * 4 + 1], nullptr, proj, R, 512, 512);
        k_add_ln<<<dim3(R), 256, 0, st>>>(x, proj, ln1 + (long)l * 1024, x2);
        k_gemm_mfma<128, 1, 0><<<dim3(16, gy1), 256, 0, st>>>(x2, wts[l * 4 + 2], nullptr, h1, R, 2048, 512);
        k_gemm_mfma<64, 0, 0><<<dim3(4, gy0), 256, 0, st>>>(h1, wts[l * 4 + 3], nullptr, proj, R, 512, 2048);
        k_add_ln<<<dim3(R), 256, 0, st>>>(x2, proj, ln2 + (long)l * 1024, x);
    }
}

extern "C" void kernel_launch(void* const* d_in, const int* in_sizes, int n_in,
                              void* d_out, int out_size, void* d_ws, size_t ws_size,
                              hipStream_t stream) {
    (void)in_sizes; (void)n_in; (void)out_size; (void)ws_size;
    const int*   token_ids    = (const int*)d_in[0];
    const int*   num_chunks   = (const int*)d_in[1];
    const int*   num_tokens   = (const int*)d_in[2];
    const float* tok_emb      = (const float*)d_in[3];
    const float* tok_emb_ln   = (const float*)d_in[4];
    const float* chunk_pos    = (const float*)d_in[5];
    const float* chunk_emb_ln = (const float*)d_in[6];
    const float* sos          = (const float*)d_in[7];
    const float* dec_emb      = (const float*)d_in[8];
    const float* dec_emb_ln   = (const float*)d_in[9];
    const float* cls_dense    = (const float*)d_in[10];
    const float* cls_ln       = (const float*)d_in[11];
    const float* cls_proj     = (const float*)d_in[12];
    const float* cls_b        = (const float*)d_in[13];
    const float* w_in[3][4] = {
        {(const float*)d_in[14], (const float*)d_in[15], (const float*)d_in[17], (const float*)d_in[18]},
        {(const float*)d_in[20], (const float*)d_in[21], (const float*)d_in[23], (const float*)d_in[24]},
        {(const float*)d_in[26], (const float*)d_in[27], (const float*)d_in[29], (const float*)d_in[30]},
    };
    const float* ln_in[3][2] = {
        {(const float*)d_in[16], (const float*)d_in[19]},
        {(const float*)d_in[22], (const float*)d_in[25]},
        {(const float*)d_in[28], (const float*)d_in[31]},
    };

    // ---- workspace carve: f32 buffers then bf16 weight pool ----
    char* p = (char*)d_ws;
    auto carve_f = [&](size_t elems) {
        float* r = (float*)p;
        p += ((elems * 4 + 255) / 256) * 256;
        return r;
    };
    float* x       = carve_f(2560 * 512);
    float* qkv     = carve_f(2560 * 1536);
    float* att     = carve_f(2560 * 512);
    float* proj    = carve_f(2560 * 512);
    float* x2      = carve_f(2560 * 512);
    float* h1      = carve_f(2560 * 2048);
    float* chunk_x = carve_f(32 * 512);
    float* dec_tok = carve_f(2048 * 512);
    float* unitsre = carve_f(2016 * 512);
    float* hbuf    = carve_f(2016 * 512);
    float* ybuf    = carve_f(2016 * 512);
    auto carve_b = [&](size_t elems) {
        bf16* r = (bf16*)p;
        p += ((elems * 2 + 255) / 256) * 256;
        return r;
    };

    // ---- build transpose descriptors (and carve bf16 weight outputs) ----
    TAll ta;
    int nm = 0, tiles = 0;
    auto push = [&](const float* src, int K, int N) -> bf16* {
        bf16* dst = carve_b((size_t)K * N);
        ta.src[nm] = src; ta.dst[nm] = dst; ta.K[nm] = K; ta.N[nm] = N;
        ta.ofs[nm] = tiles;
        tiles += (K / 32) * (N / 32);
        ++nm;
        return dst;
    };
    // per-transformer weights: {qkv, wo, w1, w2} x 2 layers
    static const int KN[4][2] = {{512, 1536}, {512, 512}, {512, 2048}, {2048, 512}};
    bf16* wt[3][8];
    for (int tf = 0; tf < 3; ++tf)
        for (int l = 0; l < 2; ++l)
            for (int m = 0; m < 4; ++m) {
                int K = KN[m][0], N = KN[m][1];
                wt[tf][l * 4 + m] = push(w_in[tf][m] + (long)l * K * N, K, N);
            }
    bf16* wt_dense = push(cls_dense, 512, 512);
    bf16* wt_proj  = push(cls_proj, 512, 32000);
    ta.ofs[nm] = tiles;   // nm == NMAT == 26

    k_transpose<<<dim3(tiles), 256, 0, stream>>>(ta);

    // 1) token encoder (32 seq x 64)
    k_embed_ln<<<2048, 256, 0, stream>>>(token_ids, tok_emb, tok_emb_ln, x);
    run_encoder(stream, x, 32, 64, num_tokens, 0, wt[0], ln_in[0][0], ln_in[0][1],
                qkv, att, proj, x2, h1);
    // 2) chunk encoder (2 seq x 16)
    k_chunk_ln<<<32, 256, 0, stream>>>(x, chunk_pos, chunk_emb_ln, chunk_x);
    run_encoder(stream, chunk_x, 2, 16, num_chunks, 1, wt[1], ln_in[1][0], ln_in[1][1],
                qkv, att, proj, x2, h1);
    // 3) decoder (32 seq x 80)
    k_embed_ln<<<2048, 256, 0, stream>>>(token_ids, dec_emb, dec_emb_ln, dec_tok);
    k_dec_in<<<2560, 256, 0, stream>>>(chunk_x, sos, dec_tok, num_chunks, num_tokens, x);
    run_encoder(stream, x, 32, 80, nullptr, 1, wt[2], ln_in[2][0], ln_in[2][1],
                qkv, att, proj, x2, h1);
    // 4) head
    k_head_gather<<<2016, 256, 0, stream>>>(x, num_chunks, num_tokens, unitsre);
    k_gemm_mfma<64, 1, 0><<<dim3(4, 32), 256, 0, stream>>>(unitsre, wt_dense, nullptr, hbuf, 2016, 512, 512);
    k_add_ln<<<2016, 256, 0, stream>>>(hbuf, nullptr, cls_ln, ybuf);
    k_gemm_mfma<128, 0, 1><<<dim3(250, 16), 256, 0, stream>>>(ybuf, wt_proj, cls_b, (float*)d_out, 2016, 32000, 512);
}

// Round 5
// 747.361 us; speedup vs baseline: 3.8192x; 1.7566x over previous
//
#include <hip/hip_runtime.h>
#include <hip/hip_bf16.h>

// CodeformerLM — round 5: bf16 activations everywhere, MFMA GEMM with
// global_load_lds (16B) + both-sides XOR swizzle (linear LDS dest,
// inverse-swizzled global source, swizzled ds_read). f32 accum + f32 softmax/LN math.

typedef __hip_bfloat16 bf16;
typedef __attribute__((ext_vector_type(8))) short short8;
typedef __attribute__((ext_vector_type(4))) float f32x4;

__device__ inline float b2f(bf16 x) { return __bfloat162float(x); }
__device__ inline bf16 f2b(float x) { return __float2bfloat16(x); }
__device__ inline float gelu_f(float x) {
    return 0.5f * x * (1.f + tanhf(0.7978845608028654f * (x + 0.044715f * x * x * x)));
}

__device__ __forceinline__ void gload16(const void* g, void* l) {
    __builtin_amdgcn_global_load_lds(
        (const __attribute__((address_space(1))) unsigned int*)g,
        (__attribute__((address_space(3))) unsigned int*)l, 16, 0, 0);
}

// ---------------- batched weight transpose+convert: W[K][N] f32 -> Wt[N][K] bf16 ----------------
#define NMAT 26
struct TAll {
    const float* src[NMAT];
    bf16* dst[NMAT];
    int K[NMAT], N[NMAT];
    int ofs[NMAT + 1];
};

__global__ __launch_bounds__(256) void k_transpose(TAll ta) {
    __shared__ float tile[32][33];
    int bid = blockIdx.x;
    int m = 0;
    while (m + 1 < NMAT && bid >= ta.ofs[m + 1]) ++m;
    int local = bid - ta.ofs[m];
    int K = ta.K[m], N = ta.N[m];
    int tilesX = N >> 5;
    int tx = local % tilesX, ty = local / tilesX;
    int k0 = ty << 5, n0 = tx << 5;
    const float* src = ta.src[m];
    bf16* dst = ta.dst[m];
    int t = threadIdx.x;
    int c = t & 31, r = t >> 5;
#pragma unroll
    for (int p = 0; p < 4; ++p)
        tile[r + p * 8][c] = src[(long)(k0 + r + p * 8) * N + n0 + c];
    __syncthreads();
#pragma unroll
    for (int p = 0; p < 4; ++p)
        dst[(long)(n0 + r + p * 8) * K + k0 + c] = __float2bfloat16(tile[c][r + p * 8]);
}

// ---------------- MFMA GEMM: C[M][N] = act(A[M][K] @ Bt[N][K]^T (+bias)) ----------------
// A, Bt bf16 row-major (K contiguous). BK=64. 4 waves 2x2, 16x16x32 bf16, f32 accum.
// LDS linear [ROWS][64] shorts; swizzle byte ^= (row&7)<<4 applied on BOTH the
// global source address (staging) and the ds_read address (fragments) — involution.
template<int BM, int BN, int ACT, int BIAS, int OUTBF>
__global__ __launch_bounds__(256) void k_gemm_mfma(const bf16* __restrict__ A,
        const bf16* __restrict__ Bt, const float* __restrict__ bias,
        void* __restrict__ Cc, int M, int N, int K) {
    constexpr int WM = BM / 2, WN = BN / 2, FM = WM / 16, FN = WN / 16;
    __shared__ __align__(16) short As[BM * 64];
    __shared__ __align__(16) short Bs[BN * 64];
    int tid = threadIdx.x;
    int w = tid >> 6, l = tid & 63;
    int wm = w >> 1, wn = w & 1;
    int l16 = l & 15, kg = l >> 4;
    int m0 = blockIdx.y * BM, n0 = blockIdx.x * BN;
    int srow = l >> 3;             // row within wave's 8-row staging group
    int scol = (l & 7) * 16;       // byte col 0..112
    f32x4 acc[FM][FN];
#pragma unroll
    for (int i = 0; i < FM; ++i)
#pragma unroll
        for (int j = 0; j < FN; ++j) acc[i][j] = 0.f;

    for (int k0 = 0; k0 < K; k0 += 64) {
        // stage A: linear LDS dest (wave-uniform base + lane*16), swizzled source
#pragma unroll
        for (int p = 0; p < BM / 32; ++p) {
            int r = p * 32 + w * 8 + srow;
            gload16((const char*)A + (((long)(m0 + r) * K + k0) << 1) + (scol ^ ((r & 7) << 4)),
                    (char*)As + (p * 32 + w * 8) * 128);
        }
#pragma unroll
        for (int p = 0; p < BN / 32; ++p) {
            int r = p * 32 + w * 8 + srow;
            gload16((const char*)Bt + (((long)(n0 + r) * K + k0) << 1) + (scol ^ ((r & 7) << 4)),
                    (char*)Bs + (p * 32 + w * 8) * 128);
        }
        __syncthreads();           // drains vmcnt (gload_lds) before reads
#pragma unroll
        for (int ks = 0; ks < 2; ++ks) {
            short8 a[FM], b[FN];
#pragma unroll
            for (int i = 0; i < FM; ++i) {
                int ar = wm * WM + i * 16 + l16;
                a[i] = *reinterpret_cast<const short8*>(
                    (char*)As + ar * 128 + ((ks * 64 + kg * 16) ^ ((ar & 7) << 4)));
            }
#pragma unroll
            for (int j = 0; j < FN; ++j) {
                int br = wn * WN + j * 16 + l16;
                b[j] = *reinterpret_cast<const short8*>(
                    (char*)Bs + br * 128 + ((ks * 64 + kg * 16) ^ ((br & 7) << 4)));
            }
#pragma unroll
            for (int i = 0; i < FM; ++i)
#pragma unroll
                for (int j = 0; j < FN; ++j)
                    acc[i][j] = __builtin_amdgcn_mfma_f32_16x16x32_bf16(a[i], b[j], acc[i][j], 0, 0, 0);
        }
        __syncthreads();
    }
    // epilogue: D col = lane&15, row = (lane>>4)*4 + reg (m89-verified)
#pragma unroll
    for (int i = 0; i < FM; ++i) {
#pragma unroll
        for (int jj = 0; jj < 4; ++jj) {
            int row = m0 + wm * WM + i * 16 + kg * 4 + jj;
            if (row < M) {
#pragma unroll
                for (int j = 0; j < FN; ++j) {
                    int col = n0 + wn * WN + j * 16 + l16;
                    float v = acc[i][j][jj];
                    if (BIAS) v += bias[col];
                    if (ACT) v = gelu_f(v);
                    if (OUTBF) ((bf16*)Cc)[(long)row * N + col] = f2b(v);
                    else       ((float*)Cc)[(long)row * N + col] = v;
                }
            }
        }
    }
}

// ---------------- LayerNorm helpers (H=512, block=256, thread t -> elems 2t,2t+1) --------
__device__ inline void ln_finish(float v0, float v1, const float* __restrict__ lnw,
                                 bf16* __restrict__ outrow) {
    float s = v0 + v1, q = v0 * v0 + v1 * v1;
#pragma unroll
    for (int o = 32; o > 0; o >>= 1) { s += __shfl_xor(s, o); q += __shfl_xor(q, o); }
    __shared__ float rs[4], rq[4];
    int w = threadIdx.x >> 6;
    if ((threadIdx.x & 63) == 0) { rs[w] = s; rq[w] = q; }
    __syncthreads();
    s = rs[0] + rs[1] + rs[2] + rs[3];
    q = rq[0] + rq[1] + rq[2] + rq[3];
    float m = s * (1.f / 512.f);
    float var = q * (1.f / 512.f) - m * m;
    float inv = rsqrtf(var + 1e-7f);
    int i0 = threadIdx.x * 2, i1 = i0 + 1;
    outrow[i0] = f2b((v0 - m) * inv * lnw[i0] + lnw[512 + i0]);
    outrow[i1] = f2b((v1 - m) * inv * lnw[i1] + lnw[512 + i1]);
}

__global__ __launch_bounds__(256) void k_embed_ln(const int* __restrict__ ids,
        const float* __restrict__ emb, const float* __restrict__ lnw, bf16* __restrict__ out) {
    int row = blockIdx.x;
    const float* e = emb + (long)ids[row] * 512;
    int i0 = threadIdx.x * 2;
    ln_finish(e[i0], e[i0 + 1], lnw, out + (long)row * 512);
}

__global__ __launch_bounds__(256) void k_add_ln(const bf16* __restrict__ a, const bf16* __restrict__ b,
        const float* __restrict__ lnw, bf16* __restrict__ out) {
    int row = blockIdx.x;
    long off = (long)row * 512;
    int i0 = threadIdx.x * 2;
    float v0 = b2f(a[off + i0]), v1 = b2f(a[off + i0 + 1]);
    if (b) { v0 += b2f(b[off + i0]); v1 += b2f(b[off + i0 + 1]); }
    ln_finish(v0, v1, lnw, out + off);
}

__global__ __launch_bounds__(256) void k_chunk_ln(const bf16* __restrict__ tu, const float* __restrict__ cpos,
        const float* __restrict__ lnw, bf16* __restrict__ out) {
    int bc = blockIdx.x;
    int c = bc & 15;
    long toff = (long)bc * 64 * 512;
    int i0 = threadIdx.x * 2;
    float v0 = b2f(tu[toff + i0])     + cpos[c * 512 + i0];
    float v1 = b2f(tu[toff + i0 + 1]) + cpos[c * 512 + i0 + 1];
    ln_finish(v0, v1, lnw, out + (long)bc * 512);
}

// ---------------- Decoder-input build (bf16 rows, uint copies) ----------------
__global__ __launch_bounds__(256) void k_dec_in(const bf16* __restrict__ chunk_units,
        const float* __restrict__ sos, const bf16* __restrict__ dec_tok,
        const int* __restrict__ num_chunks, const int* __restrict__ num_tokens,
        bf16* __restrict__ out) {
    int row = blockIdx.x;          // bc*80 + p
    int p = row % 80;
    int bc = row / 80;
    int c = bc & 15, b = bc >> 4;
    int t = threadIdx.x;
    bf16* o = out + (long)row * 512;
    if (c < num_chunks[b]) {
        if (p <= c) {
            if (p == 0) {          // sos is f32 input
                o[2 * t]     = f2b(sos[2 * t]);
                o[2 * t + 1] = f2b(sos[2 * t + 1]);
                return;
            }
            const uint* s = (const uint*)(chunk_units + ((long)(b * 16 + p - 1)) * 512);
            ((uint*)o)[t] = s[t];
            return;
        }
        int n = num_tokens[bc];
        if (p <= c + n) {
            const uint* s = (const uint*)(dec_tok + ((long)bc * 64 + (p - c - 1)) * 512);
            ((uint*)o)[t] = s[t];
            return;
        }
    }
    ((uint*)o)[t] = 0u;
}

// ---------------- Head gather ----------------
__global__ __launch_bounds__(256) void k_head_gather(const bf16* __restrict__ units,
        const int* __restrict__ num_chunks, const int* __restrict__ num_tokens,
        bf16* __restrict__ out) {
    int row = blockIdx.x;          // bc*63 + t
    int t = row % 63;
    int bc = row / 63;
    int c = bc & 15, b = bc >> 4;
    bool valid = (c < num_chunks[b]) && (t < num_tokens[bc] - 1);
    uint* o = (uint*)(out + (long)row * 512);
    if (valid) {
        const uint* s = (const uint*)(units + ((long)bc * 80 + (c + 1 + t)) * 512);
        o[threadIdx.x] = s[threadIdx.x];
    } else {
        o[threadIdx.x] = 0u;
    }
}

// ---------------- Fused attention: one block per (seq, head). dh=64, NH=8, S<=80 --------
__global__ __launch_bounds__(256) void k_attn(const bf16* __restrict__ qkv, bf16* __restrict__ att,
        const int* __restrict__ limits, int causal, int S) {
    __shared__ float Qs[80][65], Ks[80][65], Vs[80][65];
    __shared__ float ps[4][80];
    int seq = blockIdx.x >> 3, h = blockIdx.x & 7;
    const bf16* base = qkv + (long)seq * S * 1536 + h * 64;
    for (int idx = threadIdx.x; idx < S * 64; idx += 256) {
        int i = idx >> 6, d = idx & 63;
        const bf16* r = base + (long)i * 1536 + d;
        Qs[i][d] = b2f(r[0]);
        Ks[i][d] = b2f(r[512]);
        Vs[i][d] = b2f(r[1024]);
    }
    __syncthreads();
    int w = threadIdx.x >> 6, lane = threadIdx.x & 63;
    int lim = limits ? limits[seq] : S;
    for (int i = w; i < S; i += 4) {
        int kmax = causal ? (i + 1) : S;
        if (lim < kmax) kmax = lim;      // kmax >= 1 always
        float s0 = -1e30f, s1 = -1e30f;
        if (lane < kmax) {
            float a = 0.f;
#pragma unroll
            for (int d = 0; d < 64; ++d) a += Qs[i][d] * Ks[lane][d];
            s0 = a * 0.125f;
        }
        if (lane + 64 < kmax) {
            float a = 0.f;
#pragma unroll
            for (int d = 0; d < 64; ++d) a += Qs[i][d] * Ks[lane + 64][d];
            s1 = a * 0.125f;
        }
        float mx = fmaxf(s0, s1);
#pragma unroll
        for (int o = 32; o > 0; o >>= 1) mx = fmaxf(mx, __shfl_xor(mx, o));
        float e0 = (lane < kmax) ? expf(s0 - mx) : 0.f;
        float e1 = (lane + 64 < kmax) ? expf(s1 - mx) : 0.f;
        float sm = e0 + e1;
#pragma unroll
        for (int o = 32; o > 0; o >>= 1) sm += __shfl_xor(sm, o);
        float rinv = 1.f / sm;
        ps[w][lane] = e0 * rinv;
        if (lane + 64 < S) ps[w][lane + 64] = e1 * rinv;
        __syncthreads();
        float acc = 0.f;
        for (int j = 0; j < kmax; ++j) acc += ps[w][j] * Vs[j][lane];
        att[((long)seq * S + i) * 512 + h * 64 + lane] = f2b(acc);
        __syncthreads();
    }
}

// ---------------- Encoder driver (L=2 layers) ----------------
static void run_encoder(hipStream_t st, bf16* x, int nseq, int S, const int* limits, int causal,
                        bf16* const* wts, const float* ln1, const float* ln2,
                        bf16* qkv, bf16* att, bf16* proj, bf16* x2, bf16* h1) {
    int R = nseq * S;
    int gy = (R + 63) / 64;
    for (int l = 0; l < 2; ++l) {
        k_gemm_mfma<64, 128, 0, 0, 1><<<dim3(12, gy), 256, 0, st>>>(x, wts[l * 4 + 0], nullptr, qkv, R, 1536, 512);
        k_attn<<<dim3(nseq * 8), 256, 0, st>>>(qkv, att, limits, causal, S);
        k_gemm_mfma<64, 64, 0, 0, 1><<<dim3(8, gy), 256, 0, st>>>(att, wts[l * 4 + 1], nullptr, proj, R, 512, 512);
        k_add_ln<<<dim3(R), 256, 0, st>>>(x, proj, ln1 + (long)l * 1024, x2);
        k_gemm_mfma<64, 128, 1, 0, 1><<<dim3(16, gy), 256, 0, st>>>(x2, wts[l * 4 + 2], nullptr, h1, R, 2048, 512);
        k_gemm_mfma<64, 64, 0, 0, 1><<<dim3(8, gy), 256, 0, st>>>(h1, wts[l * 4 + 3], nullptr, proj, R, 512, 2048);
        k_add_ln<<<dim3(R), 256, 0, st>>>(x2, proj, ln2 + (long)l * 1024, x);
    }
}

extern "C" void kernel_launch(void* const* d_in, const int* in_sizes, int n_in,
                              void* d_out, int out_size, void* d_ws, size_t ws_size,
                              hipStream_t stream) {
    (void)in_sizes; (void)n_in; (void)out_size; (void)ws_size;
    const int*   token_ids    = (const int*)d_in[0];
    const int*   num_chunks   = (const int*)d_in[1];
    const int*   num_tokens   = (const int*)d_in[2];
    const float* tok_emb      = (const float*)d_in[3];
    const float* tok_emb_ln   = (const float*)d_in[4];
    const float* chunk_pos    = (const float*)d_in[5];
    const float* chunk_emb_ln = (const float*)d_in[6];
    const float* sos          = (const float*)d_in[7];
    const float* dec_emb      = (const float*)d_in[8];
    const float* dec_emb_ln   = (const float*)d_in[9];
    const float* cls_dense    = (const float*)d_in[10];
    const float* cls_ln       = (const float*)d_in[11];
    const float* cls_proj     = (const float*)d_in[12];
    const float* cls_b        = (const float*)d_in[13];
    const float* w_in[3][4] = {
        {(const float*)d_in[14], (const float*)d_in[15], (const float*)d_in[17], (const float*)d_in[18]},
        {(const float*)d_in[20], (const float*)d_in[21], (const float*)d_in[23], (const float*)d_in[24]},
        {(const float*)d_in[26], (const float*)d_in[27], (const float*)d_in[29], (const float*)d_in[30]},
    };
    const float* ln_in[3][2] = {
        {(const float*)d_in[16], (const float*)d_in[19]},
        {(const float*)d_in[22], (const float*)d_in[25]},
        {(const float*)d_in[28], (const float*)d_in[31]},
    };

    // ---- workspace carve: bf16 activations (rows padded to tile multiples) ----
    char* p = (char*)d_ws;
    auto carve_b = [&](size_t elems) {
        bf16* r = (bf16*)p;
        p += ((elems * 2 + 255) / 256) * 256;
        return r;
    };
    bf16* x       = carve_b((size_t)2560 * 512);
    bf16* qkv     = carve_b((size_t)2560 * 1536);
    bf16* att     = carve_b((size_t)2560 * 512);
    bf16* proj    = carve_b((size_t)2560 * 512);
    bf16* x2      = carve_b((size_t)2560 * 512);
    bf16* h1      = carve_b((size_t)2560 * 2048);
    bf16* chunk_x = carve_b((size_t)64 * 512);     // padded to 64 rows (BM=64)
    bf16* dec_tok = carve_b((size_t)2048 * 512);
    bf16* unitsre = carve_b((size_t)2048 * 512);   // padded (M=2016)
    bf16* hbuf    = carve_b((size_t)2048 * 512);
    bf16* ybuf    = carve_b((size_t)2048 * 512);

    // ---- transpose descriptors (weights f32 [K][N] -> bf16 [N][K]) ----
    TAll ta;
    int nm = 0, tiles = 0;
    auto push = [&](const float* src, int K, int N) -> bf16* {
        bf16* dst = carve_b((size_t)K * N);
        ta.src[nm] = src; ta.dst[nm] = dst; ta.K[nm] = K; ta.N[nm] = N;
        ta.ofs[nm] = tiles;
        tiles += (K / 32) * (N / 32);
        ++nm;
        return dst;
    };
    static const int KN[4][2] = {{512, 1536}, {512, 512}, {512, 2048}, {2048, 512}};
    bf16* wt[3][8];
    for (int tf = 0; tf < 3; ++tf)
        for (int l = 0; l < 2; ++l)
            for (int m = 0; m < 4; ++m) {
                int K = KN[m][0], N = KN[m][1];
                wt[tf][l * 4 + m] = push(w_in[tf][m] + (long)l * K * N, K, N);
            }
    bf16* wt_dense = push(cls_dense, 512, 512);
    bf16* wt_proj  = push(cls_proj, 512, 32000);
    ta.ofs[nm] = tiles;   // nm == NMAT == 26

    k_transpose<<<dim3(tiles), 256, 0, stream>>>(ta);

    // 1) token encoder (32 seq x 64)
    k_embed_ln<<<2048, 256, 0, stream>>>(token_ids, tok_emb, tok_emb_ln, x);
    run_encoder(stream, x, 32, 64, num_tokens, 0, wt[0], ln_in[0][0], ln_in[0][1],
                qkv, att, proj, x2, h1);
    // 2) chunk encoder (2 seq x 16)
    k_chunk_ln<<<32, 256, 0, stream>>>(x, chunk_pos, chunk_emb_ln, chunk_x);
    run_encoder(stream, chunk_x, 2, 16, num_chunks, 1, wt[1], ln_in[1][0], ln_in[1][1],
                qkv, att, proj, x2, h1);
    // 3) decoder (32 seq x 80)
    k_embed_ln<<<2048, 256, 0, stream>>>(token_ids, dec_emb, dec_emb_ln, dec_tok);
    k_dec_in<<<2560, 256, 0, stream>>>(chunk_x, sos, dec_tok, num_chunks, num_tokens, x);
    run_encoder(stream, x, 32, 80, nullptr, 1, wt[2], ln_in[2][0], ln_in[2][1],
                qkv, att, proj, x2, h1);
    // 4) head
    k_head_gather<<<2016, 256, 0, stream>>>(x, num_chunks, num_tokens, unitsre);
    k_gemm_mfma<64, 64, 1, 0, 1><<<dim3(8, 32), 256, 0, stream>>>(unitsre, wt_dense, nullptr, hbuf, 2016, 512, 512);
    k_add_ln<<<2016, 256, 0, stream>>>(hbuf, nullptr, cls_ln, ybuf);
    k_gemm_mfma<128, 128, 0, 1, 0><<<dim3(250, 16), 256, 0, stream>>>(ybuf, wt_proj, cls_b, d_out, 2016, 32000, 512);
}

// Round 6
// 611.195 us; speedup vs baseline: 4.6700x; 1.2228x over previous
//
#include <hip/hip_runtime.h>
#include <hip/hip_bf16.h>

// CodeformerLM — round 6: dbuf-prefetch MFMA GEMM (counted vmcnt, raw barriers),
// MFMA attention (bf16), merged embed-LN. bf16 activations, f32 accum/softmax/LN.

typedef __hip_bfloat16 bf16;
typedef __attribute__((ext_vector_type(8))) short short8;
typedef __attribute__((ext_vector_type(4))) float f32x4;

__device__ inline float b2f(bf16 x) { return __bfloat162float(x); }
__device__ inline bf16 f2b(float x) { return __float2bfloat16(x); }
__device__ inline short f2bs(float x) { bf16 h = __float2bfloat16(x); return *reinterpret_cast<short*>(&h); }
__device__ inline float gelu_f(float x) {
    return 0.5f * x * (1.f + tanhf(0.7978845608028654f * (x + 0.044715f * x * x * x)));
}
__device__ __forceinline__ void gload16(const void* g, void* l) {
    __builtin_amdgcn_global_load_lds(
        (const __attribute__((address_space(1))) unsigned int*)g,
        (__attribute__((address_space(3))) unsigned int*)l, 16, 0, 0);
}

// ---------------- batched weight transpose+convert: W[K][N] f32 -> Wt[N][K] bf16 ----------------
#define NMAT 26
struct TAll {
    const float* src[NMAT];
    bf16* dst[NMAT];
    int K[NMAT], N[NMAT];
    int ofs[NMAT + 1];
};

__global__ __launch_bounds__(256) void k_transpose(TAll ta) {
    __shared__ float tile[32][33];
    int bid = blockIdx.x;
    int m = 0;
    while (m + 1 < NMAT && bid >= ta.ofs[m + 1]) ++m;
    int local = bid - ta.ofs[m];
    int K = ta.K[m], N = ta.N[m];
    int tilesX = N >> 5;
    int tx = local % tilesX, ty = local / tilesX;
    int k0 = ty << 5, n0 = tx << 5;
    const float* src = ta.src[m];
    bf16* dst = ta.dst[m];
    int t = threadIdx.x;
    int c = t & 31, r = t >> 5;
#pragma unroll
    for (int p = 0; p < 4; ++p)
        tile[r + p * 8][c] = src[(long)(k0 + r + p * 8) * N + n0 + c];
    __syncthreads();
#pragma unroll
    for (int p = 0; p < 4; ++p)
        dst[(long)(n0 + r + p * 8) * K + k0 + c] = __float2bfloat16(tile[c][r + p * 8]);
}

// ---------------- MFMA GEMM with double-buffer prefetch ----------------
// C[M][N] = act(A[M][K] @ Bt[N][K]^T (+bias)). LDS linear, XOR swizzle both sides.
// Main loop: issue next stage, s_waitcnt vmcnt(L) (prev stage done, next in flight),
// barrier, compute, lgkmcnt(0)+sched_barrier+barrier. Never drains vmcnt mid-loop.
template<int BM, int BN, int ACT, int BIAS, int OUTBF>
__global__ __launch_bounds__(256) void k_gemm_mfma(const bf16* __restrict__ A,
        const bf16* __restrict__ Bt, const float* __restrict__ bias,
        void* __restrict__ Cc, int M, int N, int K) {
    constexpr int WM = BM / 2, WN = BN / 2, FM = WM / 16, FN = WN / 16;
    constexpr int L = BM / 32 + BN / 32;     // gload_lds instrs per wave per stage
    constexpr int ASZ = BM * 64, BSZ = BN * 64;  // shorts per buffer
    __shared__ __align__(16) short As[2 * ASZ];
    __shared__ __align__(16) short Bs[2 * BSZ];
    int tid = threadIdx.x;
    int w = tid >> 6, l = tid & 63;
    int wm = w >> 1, wn = w & 1;
    int l16 = l & 15, kg = l >> 4;
    int m0 = blockIdx.y * BM, n0 = blockIdx.x * BN;
    int srow = l >> 3, scol = (l & 7) * 16;
    f32x4 acc[FM][FN];
#pragma unroll
    for (int i = 0; i < FM; ++i)
#pragma unroll
        for (int j = 0; j < FN; ++j) acc[i][j] = 0.f;

    auto stage = [&](int kt, int half) {
        long kof = (long)kt * 64;
#pragma unroll
        for (int p = 0; p < BM / 32; ++p) {
            int r = p * 32 + w * 8 + srow;
            gload16((const char*)A + (((long)(m0 + r) * K + kof) << 1) + (scol ^ ((r & 7) << 4)),
                    (char*)As + half * (ASZ * 2) + (p * 32 + w * 8) * 128);
        }
#pragma unroll
        for (int p = 0; p < BN / 32; ++p) {
            int r = p * 32 + w * 8 + srow;
            gload16((const char*)Bt + (((long)(n0 + r) * K + kof) << 1) + (scol ^ ((r & 7) << 4)),
                    (char*)Bs + half * (BSZ * 2) + (p * 32 + w * 8) * 128);
        }
    };

    int NT = K >> 6;
    stage(0, 0);
    for (int t = 0; t < NT; ++t) {
        int cur = t & 1;
        if (t + 1 < NT) {
            stage(t + 1, cur ^ 1);
            if constexpr (L == 4)      asm volatile("s_waitcnt vmcnt(4)" ::: "memory");
            else if constexpr (L == 6) asm volatile("s_waitcnt vmcnt(6)" ::: "memory");
            else                       asm volatile("s_waitcnt vmcnt(8)" ::: "memory");
        } else {
            asm volatile("s_waitcnt vmcnt(0)" ::: "memory");
        }
        __builtin_amdgcn_s_barrier();
        const char* Ab = (const char*)As + cur * (ASZ * 2);
        const char* Bb = (const char*)Bs + cur * (BSZ * 2);
#pragma unroll
        for (int ks = 0; ks < 2; ++ks) {
            short8 a[FM], b[FN];
#pragma unroll
            for (int i = 0; i < FM; ++i) {
                int ar = wm * WM + i * 16 + l16;
                a[i] = *reinterpret_cast<const short8*>(Ab + ar * 128 + ((ks * 64 + kg * 16) ^ ((ar & 7) << 4)));
            }
#pragma unroll
            for (int j = 0; j < FN; ++j) {
                int br = wn * WN + j * 16 + l16;
                b[j] = *reinterpret_cast<const short8*>(Bb + br * 128 + ((ks * 64 + kg * 16) ^ ((br & 7) << 4)));
            }
#pragma unroll
            for (int i = 0; i < FM; ++i)
#pragma unroll
                for (int j = 0; j < FN; ++j)
                    acc[i][j] = __builtin_amdgcn_mfma_f32_16x16x32_bf16(a[i], b[j], acc[i][j], 0, 0, 0);
        }
        asm volatile("s_waitcnt lgkmcnt(0)" ::: "memory");
        __builtin_amdgcn_sched_barrier(0);
        __builtin_amdgcn_s_barrier();
    }
    // epilogue: D col=lane&15, row=(lane>>4)*4+reg
#pragma unroll
    for (int i = 0; i < FM; ++i) {
#pragma unroll
        for (int jj = 0; jj < 4; ++jj) {
            int row = m0 + wm * WM + i * 16 + kg * 4 + jj;
            if (row < M) {
#pragma unroll
                for (int j = 0; j < FN; ++j) {
                    int col = n0 + wn * WN + j * 16 + l16;
                    float v = acc[i][j][jj];
                    if (BIAS) v += bias[col];
                    if (ACT) v = gelu_f(v);
                    if (OUTBF) ((bf16*)Cc)[(long)row * N + col] = f2b(v);
                    else       ((float*)Cc)[(long)row * N + col] = v;
                }
            }
        }
    }
}

// ---------------- MFMA attention: one block per (seq, head). dh=64, NH=8 ----------------
// Q/K LDS rows stride 72 shorts; V transposed [64][104]; P per-wave [16][104].
// QK^T: A=Q-frag, B=K-frag (same layouts as GEMM). Softmax in-register (keys
// spread across l16 lanes -> shfl_xor 1,2,4,8). PV: A=P (via LDS), B=Vt rows.
template<int S>
__global__ __launch_bounds__(256) void k_attn_mfma(const bf16* __restrict__ qkv,
        bf16* __restrict__ att, const int* __restrict__ limits, int causal) {
    constexpr int KT = S / 16;                 // score col-tiles (== q-tiles)
    constexpr int SP = ((S + 31) / 32) * 32;   // keys padded to 32
    constexpr int KS = SP / 32;                // PV k-steps
    constexpr int SPAD = SP - KT * 16;         // zero-pad key cols (0 or 16)
    __shared__ __align__(16) short Qs[S * 72];
    __shared__ __align__(16) short Ks[S * 72];
    __shared__ __align__(16) short Vt[64 * 104];
    __shared__ __align__(16) short Pw[4][16 * 104];
    int seq = blockIdx.x >> 3, h = blockIdx.x & 7;
    int tid = threadIdx.x;
    const short* base = (const short*)qkv + (long)seq * S * 1536 + h * 64;
    for (int idx = tid; idx < S * 8; idx += 256) {
        int i = idx >> 3, c = idx & 7;
        const short* r = base + (long)i * 1536 + c * 8;
        *reinterpret_cast<short8*>(&Qs[i * 72 + c * 8]) = *reinterpret_cast<const short8*>(r);
        *reinterpret_cast<short8*>(&Ks[i * 72 + c * 8]) = *reinterpret_cast<const short8*>(r + 512);
    }
    for (int idx = tid; idx < S * 64; idx += 256) {
        int i = idx >> 6, d = idx & 63;
        Vt[d * 104 + i] = base[(long)i * 1536 + 1024 + d];
    }
    if (SPAD > 0)
        for (int idx = tid; idx < SPAD * 64; idx += 256) {
            int d = idx >> 4, kk = idx & 15;
            Vt[d * 104 + S + kk] = 0;
        }
    __syncthreads();
    int w = tid >> 6, l = tid & 63;
    int l16 = l & 15, kg = l >> 4;
    int lim = limits ? limits[seq] : S;
    for (int qt = w; qt < KT; qt += 4) {
        // --- QK^T ---
        f32x4 sc[KT];
#pragma unroll
        for (int kt = 0; kt < KT; ++kt) sc[kt] = 0.f;
#pragma unroll
        for (int ks = 0; ks < 2; ++ks) {
            short8 qa = *reinterpret_cast<const short8*>((const char*)Qs + (qt * 16 + l16) * 144 + ks * 64 + kg * 16);
#pragma unroll
            for (int kt = 0; kt < KT; ++kt) {
                short8 kb = *reinterpret_cast<const short8*>((const char*)Ks + (kt * 16 + l16) * 144 + ks * 64 + kg * 16);
                sc[kt] = __builtin_amdgcn_mfma_f32_16x16x32_bf16(qa, kb, sc[kt], 0, 0, 0);
            }
        }
        // --- softmax (per jj row; keys at col=l16 across kt tiles) ---
#pragma unroll
        for (int jj = 0; jj < 4; ++jj) {
            int q = qt * 16 + kg * 4 + jj;
            float vs[KT], m = -1e30f;
#pragma unroll
            for (int kt = 0; kt < KT; ++kt) {
                int key = kt * 16 + l16;
                float s = sc[kt][jj] * 0.125f;
                bool ok = (!causal || key <= q) && (key < lim);
                vs[kt] = ok ? s : -1e30f;
                m = fmaxf(m, vs[kt]);
            }
#pragma unroll
            for (int o = 1; o < 16; o <<= 1) m = fmaxf(m, __shfl_xor(m, o));
            float sum = 0.f;
#pragma unroll
            for (int kt = 0; kt < KT; ++kt) { vs[kt] = __expf(vs[kt] - m); sum += vs[kt]; }
#pragma unroll
            for (int o = 1; o < 16; o <<= 1) sum += __shfl_xor(sum, o);
            float rinv = 1.f / sum;
#pragma unroll
            for (int kt = 0; kt < KT; ++kt)
                Pw[w][(kg * 4 + jj) * 104 + kt * 16 + l16] = f2bs(vs[kt] * rinv);
        }
        if (SPAD > 0) {
#pragma unroll
            for (int jj = 0; jj < 4; ++jj)
                Pw[w][(kg * 4 + jj) * 104 + KT * 16 + l16] = 0;
        }
        // --- PV ---
        f32x4 ao[4];
#pragma unroll
        for (int ct = 0; ct < 4; ++ct) ao[ct] = 0.f;
#pragma unroll
        for (int kst = 0; kst < KS; ++kst) {
            short8 pa = *reinterpret_cast<const short8*>((const char*)&Pw[w][0] + l16 * 208 + kst * 64 + kg * 16);
#pragma unroll
            for (int ct = 0; ct < 4; ++ct) {
                short8 vb = *reinterpret_cast<const short8*>((const char*)Vt + (ct * 16 + l16) * 208 + kst * 64 + kg * 16);
                ao[ct] = __builtin_amdgcn_mfma_f32_16x16x32_bf16(pa, vb, ao[ct], 0, 0, 0);
            }
        }
#pragma unroll
        for (int ct = 0; ct < 4; ++ct)
#pragma unroll
            for (int jj = 0; jj < 4; ++jj) {
                int q = qt * 16 + kg * 4 + jj;
                att[((long)seq * S + q) * 512 + h * 64 + ct * 16 + l16] = f2b(ao[ct][jj]);
            }
    }
}

// ---------------- LayerNorm helpers ----------------
__device__ inline void ln_finish(float v0, float v1, const float* __restrict__ lnw,
                                 bf16* __restrict__ outrow) {
    float s = v0 + v1, q = v0 * v0 + v1 * v1;
#pragma unroll
    for (int o = 32; o > 0; o >>= 1) { s += __shfl_xor(s, o); q += __shfl_xor(q, o); }
    __shared__ float rs[4], rq[4];
    int w = threadIdx.x >> 6;
    if ((threadIdx.x & 63) == 0) { rs[w] = s; rq[w] = q; }
    __syncthreads();
    s = rs[0] + rs[1] + rs[2] + rs[3];
    q = rq[0] + rq[1] + rq[2] + rq[3];
    float m = s * (1.f / 512.f);
    float var = q * (1.f / 512.f) - m * m;
    float inv = rsqrtf(var + 1e-7f);
    int i0 = threadIdx.x * 2, i1 = i0 + 1;
    outrow[i0] = f2b((v0 - m) * inv * lnw[i0] + lnw[512 + i0]);
    outrow[i1] = f2b((v1 - m) * inv * lnw[i1] + lnw[512 + i1]);
}

// merged tok+dec embedding LN (rows 0..2047: tok, 2048..4095: dec)
__global__ __launch_bounds__(256) void k_embed_ln2(const int* __restrict__ ids,
        const float* __restrict__ tok_emb, const float* __restrict__ tok_lnw,
        const float* __restrict__ dec_emb, const float* __restrict__ dec_lnw,
        bf16* __restrict__ x, bf16* __restrict__ dec_tok) {
    int row = blockIdx.x;
    const float* emb; const float* lnw; bf16* out;
    if (row < 2048) { emb = tok_emb; lnw = tok_lnw; out = x + (long)row * 512; }
    else { row -= 2048; emb = dec_emb; lnw = dec_lnw; out = dec_tok + (long)row * 512; }
    const float* e = emb + (long)ids[row] * 512;
    int i0 = threadIdx.x * 2;
    ln_finish(e[i0], e[i0 + 1], lnw, out);
}

__global__ __launch_bounds__(256) void k_add_ln(const bf16* __restrict__ a, const bf16* __restrict__ b,
        const float* __restrict__ lnw, bf16* __restrict__ out) {
    int row = blockIdx.x;
    long off = (long)row * 512;
    int i0 = threadIdx.x * 2;
    float v0 = b2f(a[off + i0]), v1 = b2f(a[off + i0 + 1]);
    if (b) { v0 += b2f(b[off + i0]); v1 += b2f(b[off + i0 + 1]); }
    ln_finish(v0, v1, lnw, out + off);
}

__global__ __launch_bounds__(256) void k_chunk_ln(const bf16* __restrict__ tu, const float* __restrict__ cpos,
        const float* __restrict__ lnw, bf16* __restrict__ out) {
    int bc = blockIdx.x;
    int c = bc & 15;
    long toff = (long)bc * 64 * 512;
    int i0 = threadIdx.x * 2;
    float v0 = b2f(tu[toff + i0])     + cpos[c * 512 + i0];
    float v1 = b2f(tu[toff + i0 + 1]) + cpos[c * 512 + i0 + 1];
    ln_finish(v0, v1, lnw, out + (long)bc * 512);
}

// ---------------- Decoder-input build ----------------
__global__ __launch_bounds__(256) void k_dec_in(const bf16* __restrict__ chunk_units,
        const float* __restrict__ sos, const bf16* __restrict__ dec_tok,
        const int* __restrict__ num_chunks, const int* __restrict__ num_tokens,
        bf16* __restrict__ out) {
    int row = blockIdx.x;
    int p = row % 80;
    int bc = row / 80;
    int c = bc & 15, b = bc >> 4;
    int t = threadIdx.x;
    bf16* o = out + (long)row * 512;
    if (c < num_chunks[b]) {
        if (p <= c) {
            if (p == 0) {
                o[2 * t]     = f2b(sos[2 * t]);
                o[2 * t + 1] = f2b(sos[2 * t + 1]);
                return;
            }
            ((uint*)o)[t] = ((const uint*)(chunk_units + ((long)(b * 16 + p - 1)) * 512))[t];
            return;
        }
        int n = num_tokens[bc];
        if (p <= c + n) {
            ((uint*)o)[t] = ((const uint*)(dec_tok + ((long)bc * 64 + (p - c - 1)) * 512))[t];
            return;
        }
    }
    ((uint*)o)[t] = 0u;
}

// ---------------- Head gather ----------------
__global__ __launch_bounds__(256) void k_head_gather(const bf16* __restrict__ units,
        const int* __restrict__ num_chunks, const int* __restrict__ num_tokens,
        bf16* __restrict__ out) {
    int row = blockIdx.x;
    int t = row % 63;
    int bc = row / 63;
    int c = bc & 15, b = bc >> 4;
    bool valid = (c < num_chunks[b]) && (t < num_tokens[bc] - 1);
    uint* o = (uint*)(out + (long)row * 512);
    if (valid) {
        o[threadIdx.x] = ((const uint*)(units + ((long)bc * 80 + (c + 1 + t)) * 512))[threadIdx.x];
    } else {
        o[threadIdx.x] = 0u;
    }
}

// ---------------- Encoder driver (L=2 layers) ----------------
template<int S>
static void run_encoder(hipStream_t st, bf16* x, int nseq, const int* limits, int causal,
                        bf16* const* wts, const float* ln1, const float* ln2,
                        bf16* qkv, bf16* att, bf16* proj, bf16* x2, bf16* h1) {
    int R = nseq * S;
    int gy = (R + 63) / 64;
    for (int l = 0; l < 2; ++l) {
        k_gemm_mfma<64, 128, 0, 0, 1><<<dim3(12, gy), 256, 0, st>>>(x, wts[l * 4 + 0], nullptr, qkv, R, 1536, 512);
        k_attn_mfma<S><<<dim3(nseq * 8), 256, 0, st>>>(qkv, att, limits, causal);
        k_gemm_mfma<64, 64, 0, 0, 1><<<dim3(8, gy), 256, 0, st>>>(att, wts[l * 4 + 1], nullptr, proj, R, 512, 512);
        k_add_ln<<<dim3(R), 256, 0, st>>>(x, proj, ln1 + (long)l * 1024, x2);
        k_gemm_mfma<64, 128, 1, 0, 1><<<dim3(16, gy), 256, 0, st>>>(x2, wts[l * 4 + 2], nullptr, h1, R, 2048, 512);
        k_gemm_mfma<64, 64, 0, 0, 1><<<dim3(8, gy), 256, 0, st>>>(h1, wts[l * 4 + 3], nullptr, proj, R, 512, 2048);
        k_add_ln<<<dim3(R), 256, 0, st>>>(x2, proj, ln2 + (long)l * 1024, x);
    }
}

extern "C" void kernel_launch(void* const* d_in, const int* in_sizes, int n_in,
                              void* d_out, int out_size, void* d_ws, size_t ws_size,
                              hipStream_t stream) {
    (void)in_sizes; (void)n_in; (void)out_size; (void)ws_size;
    const int*   token_ids    = (const int*)d_in[0];
    const int*   num_chunks   = (const int*)d_in[1];
    const int*   num_tokens   = (const int*)d_in[2];
    const float* tok_emb      = (const float*)d_in[3];
    const float* tok_emb_ln   = (const float*)d_in[4];
    const float* chunk_pos    = (const float*)d_in[5];
    const float* chunk_emb_ln = (const float*)d_in[6];
    const float* sos          = (const float*)d_in[7];
    const float* dec_emb      = (const float*)d_in[8];
    const float* dec_emb_ln   = (const float*)d_in[9];
    const float* cls_dense    = (const float*)d_in[10];
    const float* cls_ln       = (const float*)d_in[11];
    const float* cls_proj     = (const float*)d_in[12];
    const float* cls_b        = (const float*)d_in[13];
    const float* w_in[3][4] = {
        {(const float*)d_in[14], (const float*)d_in[15], (const float*)d_in[17], (const float*)d_in[18]},
        {(const float*)d_in[20], (const float*)d_in[21], (const float*)d_in[23], (const float*)d_in[24]},
        {(const float*)d_in[26], (const float*)d_in[27], (const float*)d_in[29], (const float*)d_in[30]},
    };
    const float* ln_in[3][2] = {
        {(const float*)d_in[16], (const float*)d_in[19]},
        {(const float*)d_in[22], (const float*)d_in[25]},
        {(const float*)d_in[28], (const float*)d_in[31]},
    };

    char* p = (char*)d_ws;
    auto carve_b = [&](size_t elems) {
        bf16* r = (bf16*)p;
        p += ((elems * 2 + 255) / 256) * 256;
        return r;
    };
    bf16* x       = carve_b((size_t)2560 * 512);
    bf16* qkv     = carve_b((size_t)2560 * 1536);
    bf16* att     = carve_b((size_t)2560 * 512);
    bf16* proj    = carve_b((size_t)2560 * 512);
    bf16* x2      = carve_b((size_t)2560 * 512);
    bf16* h1      = carve_b((size_t)2560 * 2048);
    bf16* chunk_x = carve_b((size_t)64 * 512);
    bf16* dec_tok = carve_b((size_t)2048 * 512);
    bf16* unitsre = carve_b((size_t)2048 * 512);
    bf16* hbuf    = carve_b((size_t)2048 * 512);
    bf16* ybuf    = carve_b((size_t)2048 * 512);

    TAll ta;
    int nm = 0, tiles = 0;
    auto push = [&](const float* src, int K, int N) -> bf16* {
        bf16* dst = carve_b((size_t)K * N);
        ta.src[nm] = src; ta.dst[nm] = dst; ta.K[nm] = K; ta.N[nm] = N;
        ta.ofs[nm] = tiles;
        tiles += (K / 32) * (N / 32);
        ++nm;
        return dst;
    };
    static const int KN[4][2] = {{512, 1536}, {512, 512}, {512, 2048}, {2048, 512}};
    bf16* wt[3][8];
    for (int tf = 0; tf < 3; ++tf)
        for (int l = 0; l < 2; ++l)
            for (int m = 0; m < 4; ++m) {
                int K = KN[m][0], N = KN[m][1];
                wt[tf][l * 4 + m] = push(w_in[tf][m] + (long)l * K * N, K, N);
            }
    bf16* wt_dense = push(cls_dense, 512, 512);
    bf16* wt_proj  = push(cls_proj, 512, 32000);
    ta.ofs[nm] = tiles;   // nm == NMAT == 26

    k_transpose<<<dim3(tiles), 256, 0, stream>>>(ta);

    // embeddings (tok + dec merged)
    k_embed_ln2<<<4096, 256, 0, stream>>>(token_ids, tok_emb, tok_emb_ln, dec_emb, dec_emb_ln, x, dec_tok);

    // 1) token encoder (32 seq x 64)
    run_encoder<64>(stream, x, 32, num_tokens, 0, wt[0], ln_in[0][0], ln_in[0][1],
                    qkv, att, proj, x2, h1);
    // 2) chunk encoder (2 seq x 16)
    k_chunk_ln<<<32, 256, 0, stream>>>(x, chunk_pos, chunk_emb_ln, chunk_x);
    run_encoder<16>(stream, chunk_x, 2, num_chunks, 1, wt[1], ln_in[1][0], ln_in[1][1],
                    qkv, att, proj, x2, h1);
    // 3) decoder (32 seq x 80)
    k_dec_in<<<2560, 256, 0, stream>>>(chunk_x, sos, dec_tok, num_chunks, num_tokens, x);
    run_encoder<80>(stream, x, 32, nullptr, 1, wt[2], ln_in[2][0], ln_in[2][1],
                    qkv, att, proj, x2, h1);
    // 4) head
    k_head_gather<<<2016, 256, 0, stream>>>(x, num_chunks, num_tokens, unitsre);
    k_gemm_mfma<64, 64, 1, 0, 1><<<dim3(8, 32), 256, 0, stream>>>(unitsre, wt_dense, nullptr, hbuf, 2016, 512, 512);
    k_add_ln<<<2016, 256, 0, stream>>>(hbuf, nullptr, cls_ln, ybuf);
    k_gemm_mfma<128, 128, 0, 1, 0><<<dim3(250, 16), 256, 0, stream>>>(ybuf, wt_proj, cls_b, d_out, 2016, 32000, 512);
}

// Round 7
// 598.587 us; speedup vs baseline: 4.7684x; 1.0211x over previous
//
#include <hip/hip_runtime.h>
#include <hip/hip_bf16.h>

// CodeformerLM — round 7: XCD-swizzled logits GEMM, barrier-free 1-wave attention
// (V transposed in qkv-GEMM epilogue), BN=64 encoder GEMMs. bf16 acts, f32 accum.

typedef __hip_bfloat16 bf16;
typedef __attribute__((ext_vector_type(8))) short short8;
typedef __attribute__((ext_vector_type(4))) float f32x4;

__device__ inline float b2f(bf16 x) { return __bfloat162float(x); }
__device__ inline bf16 f2b(float x) { return __float2bfloat16(x); }
__device__ inline short f2bs(float x) { bf16 h = __float2bfloat16(x); return *reinterpret_cast<short*>(&h); }
__device__ inline float gelu_f(float x) {
    return 0.5f * x * (1.f + tanhf(0.7978845608028654f * (x + 0.044715f * x * x * x)));
}
__device__ __forceinline__ void gload16(const void* g, void* l) {
    __builtin_amdgcn_global_load_lds(
        (const __attribute__((address_space(1))) unsigned int*)g,
        (__attribute__((address_space(3))) unsigned int*)l, 16, 0, 0);
}

// ---------------- batched weight transpose+convert: W[K][N] f32 -> Wt[N][K] bf16 ----------------
#define NMAT 26
struct TAll {
    const float* src[NMAT];
    bf16* dst[NMAT];
    int K[NMAT], N[NMAT];
    int ofs[NMAT + 1];
};

__global__ __launch_bounds__(256) void k_transpose(TAll ta) {
    __shared__ float tile[32][33];
    int bid = blockIdx.x;
    int m = 0;
    while (m + 1 < NMAT && bid >= ta.ofs[m + 1]) ++m;
    int local = bid - ta.ofs[m];
    int K = ta.K[m], N = ta.N[m];
    int tilesX = N >> 5;
    int tx = local % tilesX, ty = local / tilesX;
    int k0 = ty << 5, n0 = tx << 5;
    const float* src = ta.src[m];
    bf16* dst = ta.dst[m];
    int t = threadIdx.x;
    int c = t & 31, r = t >> 5;
#pragma unroll
    for (int p = 0; p < 4; ++p)
        tile[r + p * 8][c] = src[(long)(k0 + r + p * 8) * N + n0 + c];
    __syncthreads();
#pragma unroll
    for (int p = 0; p < 4; ++p)
        dst[(long)(n0 + r + p * 8) * K + k0 + c] = __float2bfloat16(tile[c][r + p * 8]);
}

// ---------------- MFMA GEMM (dbuf prefetch, counted vmcnt, raw barriers) ----------------
// C[M][N] = act(A[M][K] @ Bt[N][K]^T (+bias)). XOR swizzle both sides.
// VT: redirect cols>=1024 (V third of qkv) to vt[seqh][d][key] transposed.
// SWZ: XCD co-location remap for grid (16,256) — all m-tiles of an n-tile on one XCD.
template<int BM, int BN, int ACT, int BIAS, int OUTBF, int VT = 0, int SWZ = 0>
__global__ __launch_bounds__(256) void k_gemm_mfma(const bf16* __restrict__ A,
        const bf16* __restrict__ Bt, const float* __restrict__ bias,
        void* __restrict__ Cc, int M, int N, int K, bf16* __restrict__ vt, int S) {
    constexpr int WM = BM / 2, WN = BN / 2, FM = WM / 16, FN = WN / 16;
    constexpr int L = BM / 32 + BN / 32;
    constexpr int ASZ = BM * 64, BSZ = BN * 64;
    __shared__ __align__(16) short As[2 * ASZ];
    __shared__ __align__(16) short Bs[2 * BSZ];
    int m0, n0;
    if constexpr (SWZ) {
        int pI = blockIdx.y * 16 + blockIdx.x;
        int q = pI >> 7, r = pI & 127;
        int mt = r >> 3, nt = q * 8 + (r & 7);
        if (nt * BN >= N) return;
        m0 = mt * BM; n0 = nt * BN;
    } else {
        m0 = blockIdx.y * BM; n0 = blockIdx.x * BN;
    }
    int tid = threadIdx.x;
    int w = tid >> 6, l = tid & 63;
    int wm = w >> 1, wn = w & 1;
    int l16 = l & 15, kg = l >> 4;
    int srow = l >> 3, scol = (l & 7) * 16;
    f32x4 acc[FM][FN];
#pragma unroll
    for (int i = 0; i < FM; ++i)
#pragma unroll
        for (int j = 0; j < FN; ++j) acc[i][j] = 0.f;

    auto stage = [&](int kt, int half) {
        long kof = (long)kt * 64;
#pragma unroll
        for (int p = 0; p < BM / 32; ++p) {
            int r = p * 32 + w * 8 + srow;
            gload16((const char*)A + (((long)(m0 + r) * K + kof) << 1) + (scol ^ ((r & 7) << 4)),
                    (char*)As + half * (ASZ * 2) + (p * 32 + w * 8) * 128);
        }
#pragma unroll
        for (int p = 0; p < BN / 32; ++p) {
            int r = p * 32 + w * 8 + srow;
            gload16((const char*)Bt + (((long)(n0 + r) * K + kof) << 1) + (scol ^ ((r & 7) << 4)),
                    (char*)Bs + half * (BSZ * 2) + (p * 32 + w * 8) * 128);
        }
    };

    int NT = K >> 6;
    stage(0, 0);
    for (int t = 0; t < NT; ++t) {
        int cur = t & 1;
        if (t + 1 < NT) {
            stage(t + 1, cur ^ 1);
            if constexpr (L == 3)      asm volatile("s_waitcnt vmcnt(3)" ::: "memory");
            else if constexpr (L == 4) asm volatile("s_waitcnt vmcnt(4)" ::: "memory");
            else if constexpr (L == 6) asm volatile("s_waitcnt vmcnt(6)" ::: "memory");
            else                       asm volatile("s_waitcnt vmcnt(8)" ::: "memory");
        } else {
            asm volatile("s_waitcnt vmcnt(0)" ::: "memory");
        }
        __builtin_amdgcn_s_barrier();
        const char* Ab = (const char*)As + cur * (ASZ * 2);
        const char* Bb = (const char*)Bs + cur * (BSZ * 2);
#pragma unroll
        for (int ks = 0; ks < 2; ++ks) {
            short8 a[FM], b[FN];
#pragma unroll
            for (int i = 0; i < FM; ++i) {
                int ar = wm * WM + i * 16 + l16;
                a[i] = *reinterpret_cast<const short8*>(Ab + ar * 128 + ((ks * 64 + kg * 16) ^ ((ar & 7) << 4)));
            }
#pragma unroll
            for (int j = 0; j < FN; ++j) {
                int br = wn * WN + j * 16 + l16;
                b[j] = *reinterpret_cast<const short8*>(Bb + br * 128 + ((ks * 64 + kg * 16) ^ ((br & 7) << 4)));
            }
#pragma unroll
            for (int i = 0; i < FM; ++i)
#pragma unroll
                for (int j = 0; j < FN; ++j)
                    acc[i][j] = __builtin_amdgcn_mfma_f32_16x16x32_bf16(a[i], b[j], acc[i][j], 0, 0, 0);
        }
        asm volatile("s_waitcnt lgkmcnt(0)" ::: "memory");
        __builtin_amdgcn_sched_barrier(0);
        __builtin_amdgcn_s_barrier();
    }
    // epilogue: D col=lane&15, row=(lane>>4)*4+reg
#pragma unroll
    for (int i = 0; i < FM; ++i) {
#pragma unroll
        for (int jj = 0; jj < 4; ++jj) {
            int row = m0 + wm * WM + i * 16 + kg * 4 + jj;
            if (row < M) {
#pragma unroll
                for (int j = 0; j < FN; ++j) {
                    int col = n0 + wn * WN + j * 16 + l16;
                    float v = acc[i][j][jj];
                    if (BIAS) v += bias[col];
                    if (ACT) v = gelu_f(v);
                    if (VT && col >= 1024) {
                        // V third -> vt[(seq*8+h)*64+d][key], key-contiguous
                        int hh = (col - 1024) >> 6, dd = (col - 1024) & 63;
                        int sq = row / S, key = row - sq * S;
                        int SPl = ((S + 31) >> 5) << 5;
                        vt[(((long)sq * 8 + hh) * 64 + dd) * SPl + key] = f2b(v);
                    } else if (OUTBF) {
                        ((bf16*)Cc)[(long)row * N + col] = f2b(v);
                    } else {
                        ((float*)Cc)[(long)row * N + col] = v;
                    }
                }
            }
        }
    }
}

// ---------------- barrier-free MFMA attention: 1 wave per (seq, head, q-tile) ----------------
// Q/K fragments direct from qkv (L2-resident); V fragments direct from vt (pre-transposed).
// Only P round-trips LDS (intra-wave, no barrier).
template<int S>
__global__ __launch_bounds__(64) void k_attn_mfma(const bf16* __restrict__ qkv,
        const bf16* __restrict__ vt, bf16* __restrict__ att,
        const int* __restrict__ limits, int causal) {
    constexpr int KT = S / 16;
    constexpr int SP = ((S + 31) / 32) * 32;
    constexpr int KS = SP / 32;
    constexpr int SPAD = SP - KT * 16;
    __shared__ __align__(16) short Pw[16 * 104];
    int bid = blockIdx.x;
    int qt = bid % KT;
    int bh = bid / KT;
    int h = bh & 7, seq = bh >> 3;
    int l = threadIdx.x;
    int l16 = l & 15, kg = l >> 4;
    int lim = limits ? limits[seq] : S;
    const short* qk = (const short*)qkv + (long)seq * S * 1536 + h * 64;
    const short* vb_base = (const short*)vt + ((long)(seq * 8 + h) * 64) * SP;

    // --- QK^T ---
    f32x4 sc[KT];
#pragma unroll
    for (int kt = 0; kt < KT; ++kt) sc[kt] = 0.f;
#pragma unroll
    for (int ks = 0; ks < 2; ++ks) {
        short8 qa = *reinterpret_cast<const short8*>(qk + (long)(qt * 16 + l16) * 1536 + ks * 32 + kg * 8);
#pragma unroll
        for (int kt = 0; kt < KT; ++kt) {
            short8 kb = *reinterpret_cast<const short8*>(qk + (long)(kt * 16 + l16) * 1536 + 512 + ks * 32 + kg * 8);
            sc[kt] = __builtin_amdgcn_mfma_f32_16x16x32_bf16(qa, kb, sc[kt], 0, 0, 0);
        }
    }
    // --- softmax (keys spread across l16; row q = kg*4+jj within tile qt) ---
#pragma unroll
    for (int jj = 0; jj < 4; ++jj) {
        int q = qt * 16 + kg * 4 + jj;
        float vs[KT], m = -1e30f;
#pragma unroll
        for (int kt = 0; kt < KT; ++kt) {
            int key = kt * 16 + l16;
            float s = sc[kt][jj] * 0.125f;
            bool ok = (!causal || key <= q) && (key < lim);
            vs[kt] = ok ? s : -1e30f;
            m = fmaxf(m, vs[kt]);
        }
#pragma unroll
        for (int o = 1; o < 16; o <<= 1) m = fmaxf(m, __shfl_xor(m, o));
        float sum = 0.f;
#pragma unroll
        for (int kt = 0; kt < KT; ++kt) { vs[kt] = __expf(vs[kt] - m); sum += vs[kt]; }
#pragma unroll
        for (int o = 1; o < 16; o <<= 1) sum += __shfl_xor(sum, o);
        float rinv = 1.f / sum;
#pragma unroll
        for (int kt = 0; kt < KT; ++kt)
            Pw[(kg * 4 + jj) * 104 + kt * 16 + l16] = f2bs(vs[kt] * rinv);
    }
    if (SPAD > 0) {
#pragma unroll
        for (int jj = 0; jj < 4; ++jj)
            Pw[(kg * 4 + jj) * 104 + KT * 16 + l16] = 0;
    }
    // --- PV: A = P rows (LDS), B = vt rows (global, key-contiguous) ---
    f32x4 ao[4];
#pragma unroll
    for (int ct = 0; ct < 4; ++ct) ao[ct] = 0.f;
#pragma unroll
    for (int kst = 0; kst < KS; ++kst) {
        short8 pa = *reinterpret_cast<const short8*>((const char*)Pw + l16 * 208 + kst * 64 + kg * 16);
#pragma unroll
        for (int ct = 0; ct < 4; ++ct) {
            short8 vbf = *reinterpret_cast<const short8*>(vb_base + (long)(ct * 16 + l16) * SP + kst * 32 + kg * 8);
            ao[ct] = __builtin_amdgcn_mfma_f32_16x16x32_bf16(pa, vbf, ao[ct], 0, 0, 0);
        }
    }
#pragma unroll
    for (int ct = 0; ct < 4; ++ct)
#pragma unroll
        for (int jj = 0; jj < 4; ++jj) {
            int q = qt * 16 + kg * 4 + jj;
            att[((long)seq * S + q) * 512 + h * 64 + ct * 16 + l16] = f2b(ao[ct][jj]);
        }
}

// ---------------- LayerNorm helpers ----------------
__device__ inline void ln_finish(float v0, float v1, const float* __restrict__ lnw,
                                 bf16* __restrict__ outrow) {
    float s = v0 + v1, q = v0 * v0 + v1 * v1;
#pragma unroll
    for (int o = 32; o > 0; o >>= 1) { s += __shfl_xor(s, o); q += __shfl_xor(q, o); }
    __shared__ float rs[4], rq[4];
    int w = threadIdx.x >> 6;
    if ((threadIdx.x & 63) == 0) { rs[w] = s; rq[w] = q; }
    __syncthreads();
    s = rs[0] + rs[1] + rs[2] + rs[3];
    q = rq[0] + rq[1] + rq[2] + rq[3];
    float m = s * (1.f / 512.f);
    float var = q * (1.f / 512.f) - m * m;
    float inv = rsqrtf(var + 1e-7f);
    int i0 = threadIdx.x * 2, i1 = i0 + 1;
    outrow[i0] = f2b((v0 - m) * inv * lnw[i0] + lnw[512 + i0]);
    outrow[i1] = f2b((v1 - m) * inv * lnw[i1] + lnw[512 + i1]);
}

__global__ __launch_bounds__(256) void k_embed_ln2(const int* __restrict__ ids,
        const float* __restrict__ tok_emb, const float* __restrict__ tok_lnw,
        const float* __restrict__ dec_emb, const float* __restrict__ dec_lnw,
        bf16* __restrict__ x, bf16* __restrict__ dec_tok) {
    int row = blockIdx.x;
    const float* emb; const float* lnw; bf16* out;
    if (row < 2048) { emb = tok_emb; lnw = tok_lnw; out = x + (long)row * 512; }
    else { row -= 2048; emb = dec_emb; lnw = dec_lnw; out = dec_tok + (long)row * 512; }
    const float* e = emb + (long)ids[row] * 512;
    int i0 = threadIdx.x * 2;
    ln_finish(e[i0], e[i0 + 1], lnw, out);
}

__global__ __launch_bounds__(256) void k_add_ln(const bf16* __restrict__ a, const bf16* __restrict__ b,
        const float* __restrict__ lnw, bf16* __restrict__ out) {
    int row = blockIdx.x;
    long off = (long)row * 512;
    int i0 = threadIdx.x * 2;
    float v0 = b2f(a[off + i0]), v1 = b2f(a[off + i0 + 1]);
    if (b) { v0 += b2f(b[off + i0]); v1 += b2f(b[off + i0 + 1]); }
    ln_finish(v0, v1, lnw, out + off);
}

__global__ __launch_bounds__(256) void k_chunk_ln(const bf16* __restrict__ tu, const float* __restrict__ cpos,
        const float* __restrict__ lnw, bf16* __restrict__ out) {
    int bc = blockIdx.x;
    int c = bc & 15;
    long toff = (long)bc * 64 * 512;
    int i0 = threadIdx.x * 2;
    float v0 = b2f(tu[toff + i0])     + cpos[c * 512 + i0];
    float v1 = b2f(tu[toff + i0 + 1]) + cpos[c * 512 + i0 + 1];
    ln_finish(v0, v1, lnw, out + (long)bc * 512);
}

// ---------------- Decoder-input build ----------------
__global__ __launch_bounds__(256) void k_dec_in(const bf16* __restrict__ chunk_units,
        const float* __restrict__ sos, const bf16* __restrict__ dec_tok,
        const int* __restrict__ num_chunks, const int* __restrict__ num_tokens,
        bf16* __restrict__ out) {
    int row = blockIdx.x;
    int p = row % 80;
    int bc = row / 80;
    int c = bc & 15, b = bc >> 4;
    int t = threadIdx.x;
    bf16* o = out + (long)row * 512;
    if (c < num_chunks[b]) {
        if (p <= c) {
            if (p == 0) {
                o[2 * t]     = f2b(sos[2 * t]);
                o[2 * t + 1] = f2b(sos[2 * t + 1]);
                return;
            }
            ((uint*)o)[t] = ((const uint*)(chunk_units + ((long)(b * 16 + p - 1)) * 512))[t];
            return;
        }
        int n = num_tokens[bc];
        if (p <= c + n) {
            ((uint*)o)[t] = ((const uint*)(dec_tok + ((long)bc * 64 + (p - c - 1)) * 512))[t];
            return;
        }
    }
    ((uint*)o)[t] = 0u;
}

// ---------------- Head gather ----------------
__global__ __launch_bounds__(256) void k_head_gather(const bf16* __restrict__ units,
        const int* __restrict__ num_chunks, const int* __restrict__ num_tokens,
        bf16* __restrict__ out) {
    int row = blockIdx.x;
    int t = row % 63;
    int bc = row / 63;
    int c = bc & 15, b = bc >> 4;
    bool valid = (c < num_chunks[b]) && (t < num_tokens[bc] - 1);
    uint* o = (uint*)(out + (long)row * 512);
    if (valid) {
        o[threadIdx.x] = ((const uint*)(units + ((long)bc * 80 + (c + 1 + t)) * 512))[threadIdx.x];
    } else {
        o[threadIdx.x] = 0u;
    }
}

// ---------------- Encoder driver (L=2 layers) ----------------
template<int S>
static void run_encoder(hipStream_t st, bf16* x, int nseq, const int* limits, int causal,
                        bf16* const* wts, const float* ln1, const float* ln2,
                        bf16* qkv, bf16* vt, bf16* att, bf16* proj, bf16* x2, bf16* h1) {
    constexpr int KT = S / 16;
    int R = nseq * S;
    int gy64 = (R + 63) / 64, gy32 = (R + 31) / 32;
    for (int l = 0; l < 2; ++l) {
        k_gemm_mfma<64, 64, 0, 0, 1, 1><<<dim3(24, gy64), 256, 0, st>>>(x, wts[l * 4 + 0], nullptr, qkv, R, 1536, 512, vt, S);
        k_attn_mfma<S><<<dim3(nseq * 8 * KT), 64, 0, st>>>(qkv, vt, att, limits, causal);
        k_gemm_mfma<32, 64, 0, 0, 1><<<dim3(8, gy32), 256, 0, st>>>(att, wts[l * 4 + 1], nullptr, proj, R, 512, 512, nullptr, 0);
        k_add_ln<<<dim3(R), 256, 0, st>>>(x, proj, ln1 + (long)l * 1024, x2);
        k_gemm_mfma<64, 64, 1, 0, 1><<<dim3(32, gy64), 256, 0, st>>>(x2, wts[l * 4 + 2], nullptr, h1, R, 2048, 512, nullptr, 0);
        k_gemm_mfma<32, 64, 0, 0, 1><<<dim3(8, gy32), 256, 0, st>>>(h1, wts[l * 4 + 3], nullptr, proj, R, 512, 2048, nullptr, 0);
        k_add_ln<<<dim3(R), 256, 0, st>>>(x2, proj, ln2 + (long)l * 1024, x);
    }
}

extern "C" void kernel_launch(void* const* d_in, const int* in_sizes, int n_in,
                              void* d_out, int out_size, void* d_ws, size_t ws_size,
                              hipStream_t stream) {
    (void)in_sizes; (void)n_in; (void)out_size; (void)ws_size;
    const int*   token_ids    = (const int*)d_in[0];
    const int*   num_chunks   = (const int*)d_in[1];
    const int*   num_tokens   = (const int*)d_in[2];
    const float* tok_emb      = (const float*)d_in[3];
    const float* tok_emb_ln   = (const float*)d_in[4];
    const float* chunk_pos    = (const float*)d_in[5];
    const float* chunk_emb_ln = (const float*)d_in[6];
    const float* sos          = (const float*)d_in[7];
    const float* dec_emb      = (const float*)d_in[8];
    const float* dec_emb_ln   = (const float*)d_in[9];
    const float* cls_dense    = (const float*)d_in[10];
    const float* cls_ln       = (const float*)d_in[11];
    const float* cls_proj     = (const float*)d_in[12];
    const float* cls_b        = (const float*)d_in[13];
    const float* w_in[3][4] = {
        {(const float*)d_in[14], (const float*)d_in[15], (const float*)d_in[17], (const float*)d_in[18]},
        {(const float*)d_in[20], (const float*)d_in[21], (const float*)d_in[23], (const float*)d_in[24]},
        {(const float*)d_in[26], (const float*)d_in[27], (const float*)d_in[29], (const float*)d_in[30]},
    };
    const float* ln_in[3][2] = {
        {(const float*)d_in[16], (const float*)d_in[19]},
        {(const float*)d_in[22], (const float*)d_in[25]},
        {(const float*)d_in[28], (const float*)d_in[31]},
    };

    char* p = (char*)d_ws;
    auto carve_b = [&](size_t elems) {
        bf16* r = (bf16*)p;
        p += ((elems * 2 + 255) / 256) * 256;
        return r;
    };
    bf16* x       = carve_b((size_t)2560 * 512);
    bf16* qkv     = carve_b((size_t)2560 * 1536);
    bf16* vt      = carve_b((size_t)32 * 8 * 64 * 96);   // max: dec SP=96
    bf16* att     = carve_b((size_t)2560 * 512);
    bf16* proj    = carve_b((size_t)2560 * 512);
    bf16* x2      = carve_b((size_t)2560 * 512);
    bf16* h1      = carve_b((size_t)2560 * 2048);
    bf16* chunk_x = carve_b((size_t)64 * 512);
    bf16* dec_tok = carve_b((size_t)2048 * 512);
    bf16* unitsre = carve_b((size_t)2048 * 512);
    bf16* hbuf    = carve_b((size_t)2048 * 512);
    bf16* ybuf    = carve_b((size_t)2048 * 512);

    TAll ta;
    int nm = 0, tiles = 0;
    auto push = [&](const float* src, int K, int N) -> bf16* {
        bf16* dst = carve_b((size_t)K * N);
        ta.src[nm] = src; ta.dst[nm] = dst; ta.K[nm] = K; ta.N[nm] = N;
        ta.ofs[nm] = tiles;
        tiles += (K / 32) * (N / 32);
        ++nm;
        return dst;
    };
    static const int KN[4][2] = {{512, 1536}, {512, 512}, {512, 2048}, {2048, 512}};
    bf16* wt[3][8];
    for (int tf = 0; tf < 3; ++tf)
        for (int l = 0; l < 2; ++l)
            for (int m = 0; m < 4; ++m) {
                int K = KN[m][0], N = KN[m][1];
                wt[tf][l * 4 + m] = push(w_in[tf][m] + (long)l * K * N, K, N);
            }
    bf16* wt_dense = push(cls_dense, 512, 512);
    bf16* wt_proj  = push(cls_proj, 512, 32000);
    ta.ofs[nm] = tiles;   // nm == NMAT == 26

    k_transpose<<<dim3(tiles), 256, 0, stream>>>(ta);

    // embeddings (tok + dec merged)
    k_embed_ln2<<<4096, 256, 0, stream>>>(token_ids, tok_emb, tok_emb_ln, dec_emb, dec_emb_ln, x, dec_tok);

    // 1) token encoder (32 seq x 64)
    run_encoder<64>(stream, x, 32, num_tokens, 0, wt[0], ln_in[0][0], ln_in[0][1],
                    qkv, vt, att, proj, x2, h1);
    // 2) chunk encoder (2 seq x 16)
    k_chunk_ln<<<32, 256, 0, stream>>>(x, chunk_pos, chunk_emb_ln, chunk_x);
    run_encoder<16>(stream, chunk_x, 2, num_chunks, 1, wt[1], ln_in[1][0], ln_in[1][1],
                    qkv, vt, att, proj, x2, h1);
    // 3) decoder (32 seq x 80)
    k_dec_in<<<2560, 256, 0, stream>>>(chunk_x, sos, dec_tok, num_chunks, num_tokens, x);
    run_encoder<80>(stream, x, 32, nullptr, 1, wt[2], ln_in[2][0], ln_in[2][1],
                    qkv, vt, att, proj, x2, h1);
    // 4) head
    k_head_gather<<<2016, 256, 0, stream>>>(x, num_chunks, num_tokens, unitsre);
    k_gemm_mfma<32, 64, 1, 0, 1><<<dim3(8, 63), 256, 0, stream>>>(unitsre, wt_dense, nullptr, hbuf, 2016, 512, 512, nullptr, 0);
    k_add_ln<<<2016, 256, 0, stream>>>(hbuf, nullptr, cls_ln, ybuf);
    // logits: XCD-swizzled grid (16 m-tiles x 256 n-slots), f32 out
    k_gemm_mfma<128, 128, 0, 1, 0, 0, 1><<<dim3(16, 256), 256, 0, stream>>>(ybuf, wt_proj, cls_b, d_out, 2016, 32000, 512, nullptr, 0);
}